// Round 5
// baseline (848.440 us; speedup 1.0000x reference)
//
#include <hip/hip_runtime.h>

// ---------------------------------------------------------------------------
// MalwareGNN: 3-layer GCN (transform -> normalized aggregate) + mean pool + FC
//   * detect int32 vs int64 indices on device (flag in ws)
//   * CSR build: deg histogram -> scan -> range-bucketed (src,dst) pairs with
//     per-block slice reservation (8 global atomics/block) -> per-range
//     scatter whose working set (1.6MB csr + 0.1MB cursor) is L2-resident
//     and whose pair stream uses non-temporal loads (no dirty-line eviction)
//   * per layer: GEMM hs = dinv*(X@W): 64-row tile, X staged in LDS k-chunks,
//     wave-uniform ds_read_b128 broadcast, W in LDS
//   * gather-aggregate: wave-per-node, lane = feature, 8x unrolled gathers
//   * self-loops analytic: out = relu(dinv*(hs[i]+sum hs[src])+b)
//   * mean-pool via per-graph binary search on sorted batch, then tiny FC
// ---------------------------------------------------------------------------

#define RGRP 8  // dst ranges

__global__ void k_detect(const unsigned* __restrict__ ei, int* __restrict__ flag) {
  __shared__ int any;
  if (threadIdx.x == 0) any = 0;
  __syncthreads();
  unsigned v = 0;
  for (int i = threadIdx.x; i < 8192; i += blockDim.x) v |= ei[2 * i + 1];
  if (v) atomicOr(&any, 1);
  __syncthreads();
  if (threadIdx.x == 0) *flag = (any == 0) ? 1 : 0;  // 1 => int64 indices
}

__device__ __forceinline__ int load_idx(const void* p, long long i, bool wide) {
  if (wide) {
    long long v = __builtin_nontemporal_load((const long long*)p + i);
    return (int)v;
  }
  return __builtin_nontemporal_load((const int*)p + i);
}

// single-pass histogram: atomics spread over N counters (0.4MB, L2/L3-fast)
__global__ void k_deg(const void* __restrict__ ei, int E, const int* __restrict__ flag,
                      int* __restrict__ deg) {
  const bool wide = (*flag != 0);
  for (int e = blockIdx.x * blockDim.x + threadIdx.x; e < E; e += gridDim.x * blockDim.x) {
    const int d = load_idx(ei, (long long)E + e, wide);
    atomicAdd(&deg[d], 1);
  }
}

__global__ void k_dinv(const int* __restrict__ deg, float* __restrict__ dinv, int N) {
  int i = blockIdx.x * blockDim.x + threadIdx.x;
  if (i < N) dinv[i] = rsqrtf((float)(deg[i] + 1));  // +1 self loop
}

// ---- exclusive scan of deg[N] -> rowptr[N+1], 2048 items/block -------------
__global__ void k_scan_a(const int* __restrict__ deg, int N, int* __restrict__ bsum) {
  __shared__ int sh[256];
  int base = blockIdx.x * 2048;
  int s = 0;
  for (int i = threadIdx.x; i < 2048; i += 256) {
    int idx = base + i;
    s += (idx < N) ? deg[idx] : 0;
  }
  sh[threadIdx.x] = s;
  __syncthreads();
  for (int off = 128; off > 0; off >>= 1) {
    if (threadIdx.x < off) sh[threadIdx.x] += sh[threadIdx.x + off];
    __syncthreads();
  }
  if (threadIdx.x == 0) bsum[blockIdx.x] = sh[0];
}

__global__ void k_scan_b(int* __restrict__ bsum, int nb) {
  if (threadIdx.x == 0) {
    int run = 0;
    for (int i = 0; i < nb; ++i) { int v = bsum[i]; bsum[i] = run; run += v; }
    bsum[nb] = run;
  }
}

__global__ void k_scan_c(const int* __restrict__ deg, int N, const int* __restrict__ bsum,
                         int* __restrict__ rowptr, int* __restrict__ cursor, int nb) {
  __shared__ int sh[256];
  int base = blockIdx.x * 2048;
  int v[8];
  int s = 0;
#pragma unroll
  for (int j = 0; j < 8; ++j) {
    int idx = base + threadIdx.x * 8 + j;
    v[j] = (idx < N) ? deg[idx] : 0;
    s += v[j];
  }
  sh[threadIdx.x] = s;
  __syncthreads();
  for (int off = 1; off < 256; off <<= 1) {
    int t = (threadIdx.x >= off) ? sh[threadIdx.x - off] : 0;
    __syncthreads();
    sh[threadIdx.x] += t;
    __syncthreads();
  }
  int excl = (threadIdx.x ? sh[threadIdx.x - 1] : 0) + bsum[blockIdx.x];
#pragma unroll
  for (int j = 0; j < 8; ++j) {
    int idx = base + threadIdx.x * 8 + j;
    if (idx < N) { rowptr[idx] = excl; cursor[idx] = excl; }
    excl += v[j];
  }
  if (blockIdx.x == gridDim.x - 1 && threadIdx.x == 255) rowptr[N] = bsum[nb];
}

// range r covers d with (8*d)/N == r; first d of range r is ceil(N*r/8)
__global__ void k_rbase(const int* __restrict__ rowptr, int* __restrict__ rb, int N) {
  int r = threadIdx.x;
  if (r <= RGRP) {
    long long lo = ((long long)N * r + RGRP - 1) / RGRP;
    if (lo > N) lo = N;
    rb[r] = rowptr[lo];
  }
}

// per-block chunk: count ranges in LDS, reserve slices (8 atomics/block),
// re-read (L2-hot) chunk, write (src,dst) pairs densely into bucket slices.
__global__ __launch_bounds__(256) void k_bucket(const void* __restrict__ ei, int E,
                                                const int* __restrict__ flag,
                                                const int* __restrict__ rb,
                                                int* __restrict__ bcur,
                                                long long* __restrict__ ebuf, int N) {
  __shared__ int sh_cnt[RGRP];
  __shared__ int sh_base[RGRP];
  __shared__ int sh_off[RGRP];
  const bool wide = (*flag != 0);
  const int chunk = (E + gridDim.x - 1) / gridDim.x;
  const int c0 = blockIdx.x * chunk;
  const int c1 = (c0 + chunk < E) ? c0 + chunk : E;
  if (threadIdx.x < RGRP) { sh_cnt[threadIdx.x] = 0; sh_off[threadIdx.x] = 0; }
  __syncthreads();
  for (int e = c0 + threadIdx.x; e < c1; e += 256) {
    const int d = load_idx(ei, (long long)E + e, wide);
    const int r = (int)(((long long)d * RGRP) / N);
    atomicAdd(&sh_cnt[r], 1);
  }
  __syncthreads();
  if (threadIdx.x < RGRP)
    sh_base[threadIdx.x] = atomicAdd(&bcur[threadIdx.x], sh_cnt[threadIdx.x]);
  __syncthreads();
  for (int e = c0 + threadIdx.x; e < c1; e += 256) {
    const int d = load_idx(ei, (long long)E + e, wide);
    const int s = load_idx(ei, e, wide);
    const int r = (int)(((long long)d * RGRP) / N);
    const int o = atomicAdd(&sh_off[r], 1);
    const long long pos = (long long)rb[r] + sh_base[r] + o;
    ebuf[pos] = ((long long)(unsigned)d << 32) | (unsigned)s;
  }
}

// per-range scatter: pair stream non-temporal; csr+cursor region L2-resident
__global__ void k_scatter2(const long long* __restrict__ ebuf, const int* __restrict__ rb,
                           int* __restrict__ cursor, int* __restrict__ csr) {
  const int r = blockIdx.x & (RGRP - 1);
  const int cblk = blockIdx.x >> 3;
  const int nch = gridDim.x >> 3;
  const int e0 = rb[r], e1 = rb[r + 1];
  for (int e = e0 + cblk * blockDim.x + threadIdx.x; e < e1; e += nch * blockDim.x) {
    const long long v = __builtin_nontemporal_load(&ebuf[e]);
    const int s = (int)v;
    const int d = (int)(v >> 32);
    const int pos = atomicAdd(&cursor[d], 1);
    csr[pos] = s;
  }
}

// ---- hs = dinv * (X @ W) ---------------------------------------------------
template <int K>
__global__ __launch_bounds__(256) void k_gemm_hs(const float* __restrict__ X,
                                                 const float* __restrict__ W,
                                                 const float* __restrict__ dinv,
                                                 float* __restrict__ HS, int N) {
  __shared__ float Wl[K * 64];
  __shared__ float Xl[64 * 32];
  for (int i = threadIdx.x; i < K * 64; i += 256) Wl[i] = W[i];
  const int col = threadIdx.x & 63;
  const int rw = threadIdx.x >> 6;
  const int srow = threadIdx.x >> 3;       // 0..31 staging row
  const int scol = (threadIdx.x & 7) * 4;  // 0,4,...,28 staging col

  const long long r0 = (long long)blockIdx.x * 64;
  const int rows = (int)((N - r0) < 64 ? (N - r0) : 64);

  float acc[16];
#pragma unroll
  for (int r = 0; r < 16; ++r) acc[r] = 0.f;

  for (int k0 = 0; k0 < K; k0 += 32) {
    __syncthreads();
#pragma unroll
    for (int p = 0; p < 2; ++p) {
      const int row = srow + p * 32;
      const int src = (row < rows) ? row : 0;  // safe tail source
      const float4 v = *(const float4*)&X[(r0 + src) * K + k0 + scol];
      *(float4*)&Xl[row * 32 + scol] = v;
    }
    __syncthreads();
#pragma unroll
    for (int kk = 0; kk < 32; kk += 4) {
      const float w0 = Wl[(k0 + kk + 0) * 64 + col];
      const float w1 = Wl[(k0 + kk + 1) * 64 + col];
      const float w2 = Wl[(k0 + kk + 2) * 64 + col];
      const float w3 = Wl[(k0 + kk + 3) * 64 + col];
#pragma unroll
      for (int r = 0; r < 16; ++r) {
        const float4 xv = *(const float4*)&Xl[(r * 4 + rw) * 32 + kk];
        acc[r] = fmaf(xv.w, w3, fmaf(xv.z, w2, fmaf(xv.y, w1, fmaf(xv.x, w0, acc[r]))));
      }
    }
  }
#pragma unroll
  for (int r = 0; r < 16; ++r) {
    const int lr = r * 4 + rw;
    if (lr < rows) {
      const long long row = r0 + lr;
      HS[row * 64 + col] = dinv[row] * acc[r];
    }
  }
}

// ---- out[i] = relu(dinv[i]*(hs[i] + sum_{src in(i)} hs[src]) + b) ----------
__global__ void k_agg(const float* __restrict__ HS, const int* __restrict__ rowptr,
                      const int* __restrict__ csr, const float* __restrict__ dinv,
                      const float* __restrict__ bias, float* __restrict__ OUT, int N) {
  const int lane = threadIdx.x & 63;
  const int wid = threadIdx.x >> 6;
  const int wavesPerBlock = blockDim.x >> 6;
  const float b = bias[lane];
  for (int node = blockIdx.x * wavesPerBlock + wid; node < N;
       node += wavesPerBlock * gridDim.x) {
    const int s0 = rowptr[node], s1 = rowptr[node + 1];
    float a0 = HS[(long long)node * 64 + lane];  // self loop
    float a1 = 0.f, a2 = 0.f, a3 = 0.f;
    for (int base = s0; base < s1; base += 64) {
      int m = s1 - base;
      if (m > 64) m = 64;
      const int idx = (base + lane < s1) ? csr[base + lane] : 0;
      int j = 0;
      for (; j + 8 <= m; j += 8) {
        const int i0 = __shfl(idx, j + 0, 64);
        const int i1 = __shfl(idx, j + 1, 64);
        const int i2 = __shfl(idx, j + 2, 64);
        const int i3 = __shfl(idx, j + 3, 64);
        const int i4 = __shfl(idx, j + 4, 64);
        const int i5 = __shfl(idx, j + 5, 64);
        const int i6 = __shfl(idx, j + 6, 64);
        const int i7 = __shfl(idx, j + 7, 64);
        const float v0 = HS[(long long)i0 * 64 + lane];
        const float v1 = HS[(long long)i1 * 64 + lane];
        const float v2 = HS[(long long)i2 * 64 + lane];
        const float v3 = HS[(long long)i3 * 64 + lane];
        const float v4 = HS[(long long)i4 * 64 + lane];
        const float v5 = HS[(long long)i5 * 64 + lane];
        const float v6 = HS[(long long)i6 * 64 + lane];
        const float v7 = HS[(long long)i7 * 64 + lane];
        a0 += v0 + v4;
        a1 += v1 + v5;
        a2 += v2 + v6;
        a3 += v3 + v7;
      }
      for (; j < m; ++j) {
        const int s = __shfl(idx, j, 64);
        a0 += HS[(long long)s * 64 + lane];
      }
    }
    OUT[(long long)node * 64 + lane] =
        fmaxf(fmaf(dinv[node], (a0 + a1) + (a2 + a3), b), 0.f);
  }
}

// ---- mean pool per graph (batch is sorted) ---------------------------------
__global__ void k_pool(const float* __restrict__ H, const void* __restrict__ batch,
                       const int* __restrict__ flag, float* __restrict__ pooled, int N) {
  __shared__ int se[2];
  __shared__ float red[4][64];
  bool wide = (*flag != 0);
  int g = blockIdx.x;
  if (threadIdx.x < 2) {
    int target = g + threadIdx.x;
    int lo = 0, hi = N;
    while (lo < hi) {
      int mid = (lo + hi) >> 1;
      long long v = wide ? ((const long long*)batch)[mid] : (long long)((const int*)batch)[mid];
      if (v < target) lo = mid + 1; else hi = mid;
    }
    se[threadIdx.x] = lo;
  }
  __syncthreads();
  int s = se[0], e = se[1];
  int lane = threadIdx.x & 63, wid = threadIdx.x >> 6;
  float acc = 0.f;
  for (int r = s + wid; r < e; r += 4) acc += H[(long long)r * 64 + lane];
  red[wid][lane] = acc;
  __syncthreads();
  if (wid == 0) {
    float v = red[0][lane] + red[1][lane] + red[2][lane] + red[3][lane];
    float cnt = (float)(e - s);
    pooled[g * 64 + lane] = v / fmaxf(cnt, 1.f);
  }
}

__global__ void k_classify(const float* __restrict__ pooled, const float* __restrict__ Wc,
                           const float* __restrict__ bc, float* __restrict__ out, int total) {
  int t = blockIdx.x * blockDim.x + threadIdx.x;
  if (t >= total) return;
  int g = t / 10, c = t % 10;
  float acc = bc[c];
#pragma unroll
  for (int h = 0; h < 64; ++h) acc += pooled[g * 64 + h] * Wc[h * 10 + c];
  out[t] = acc;
}

extern "C" void kernel_launch(void* const* d_in, const int* in_sizes, int n_in,
                              void* d_out, int out_size, void* d_ws, size_t ws_size,
                              hipStream_t stream) {
  const float* x = (const float*)d_in[0];
  const void* ei = d_in[1];
  const void* batch = d_in[2];
  const float* W1 = (const float*)d_in[3];
  const float* b1 = (const float*)d_in[4];
  const float* W2 = (const float*)d_in[5];
  const float* b2 = (const float*)d_in[6];
  const float* W3 = (const float*)d_in[7];
  const float* b3 = (const float*)d_in[8];
  const float* Wc = (const float*)d_in[9];
  const float* bc = (const float*)d_in[10];
  float* out = (float*)d_out;

  const int N = in_sizes[0] / 128;
  const int E = in_sizes[1] / 2;
  const int G = out_size / 10;
  const int NB = (N + 2047) / 2048;

  char* W = (char*)d_ws;
  size_t off = 0;
  auto take = [&](size_t b) -> void* {
    void* p = W + off;
    off += (b + 255) & ~(size_t)255;
    return p;
  };
  int* flag = (int*)take(4);
  int* deg = (int*)take((size_t)4 * N);
  int* rowptr = (int*)take((size_t)4 * (N + 1));
  int* cursor = (int*)take((size_t)4 * N);
  int* bsum = (int*)take((size_t)4 * (NB + 1));
  int* rb = (int*)take((size_t)4 * (RGRP + 1));
  int* bcur = (int*)take((size_t)4 * RGRP);
  float* dinv = (float*)take((size_t)4 * N);
  int* csr = (int*)take((size_t)4 * E);
  long long* ebuf = (long long*)take((size_t)8 * E);
  float* hs = (float*)take((size_t)4 * N * 64);
  float* cur = (float*)take((size_t)4 * N * 64);
  float* pooled = (float*)take((size_t)4 * G * 64);
  (void)ws_size;

  hipMemsetAsync(deg, 0, (size_t)4 * N, stream);
  hipMemsetAsync(bcur, 0, (size_t)4 * RGRP, stream);

  k_detect<<<1, 256, 0, stream>>>((const unsigned*)ei, flag);
  k_deg<<<2048, 256, 0, stream>>>(ei, E, flag, deg);
  k_dinv<<<(N + 255) / 256, 256, 0, stream>>>(deg, dinv, N);
  k_scan_a<<<NB, 256, 0, stream>>>(deg, N, bsum);
  k_scan_b<<<1, 64, 0, stream>>>(bsum, NB);
  k_scan_c<<<NB, 256, 0, stream>>>(deg, N, bsum, rowptr, cursor, NB);
  k_rbase<<<1, 64, 0, stream>>>(rowptr, rb, N);
  k_bucket<<<1024, 256, 0, stream>>>(ei, E, flag, rb, bcur, ebuf, N);
  k_scatter2<<<4096, 256, 0, stream>>>(ebuf, rb, cursor, csr);

  const int TILES = (N + 63) / 64;
  // layer 1: x[N,128] @ W1 -> hs; aggregate -> cur
  k_gemm_hs<128><<<TILES, 256, 0, stream>>>(x, W1, dinv, hs, N);
  k_agg<<<4096, 256, 0, stream>>>(hs, rowptr, csr, dinv, b1, cur, N);
  // layer 2
  k_gemm_hs<64><<<TILES, 256, 0, stream>>>(cur, W2, dinv, hs, N);
  k_agg<<<4096, 256, 0, stream>>>(hs, rowptr, csr, dinv, b2, cur, N);
  // layer 3
  k_gemm_hs<64><<<TILES, 256, 0, stream>>>(cur, W3, dinv, hs, N);
  k_agg<<<4096, 256, 0, stream>>>(hs, rowptr, csr, dinv, b3, cur, N);

  k_pool<<<G, 256, 0, stream>>>(cur, batch, flag, pooled, N);
  k_classify<<<(G * 10 + 255) / 256, 256, 0, stream>>>(pooled, Wc, bc, out, G * 10);
}

// Round 6
// 788.853 us; speedup vs baseline: 1.0755x; 1.0755x over previous
//
#include <hip/hip_runtime.h>

// ---------------------------------------------------------------------------
// MalwareGNN: 3-layer GCN (transform -> normalized aggregate) + mean pool + FC
//   * detect int32 vs int64 indices on device (flag in ws)
//   * CSR build with NO write amplification: every written region is owned by
//     exactly one block (count -> reserve -> dense writes), 3 levels:
//       p1 k_bucket : 8 range buckets of (dst,src) pairs
//       p2 k_bucket2: each range -> 64 sub-buckets (exact rowptr-based slices)
//       p3 k_csr    : block-per-sub-bucket, LDS cursors = rowptr[d], writes a
//                     contiguous ~25KB csr region exclusively owned by block
//   * per layer: GEMM hs = dinv*(X@W): 64-row tile, X staged in LDS k-chunks,
//     wave-uniform ds_read_b128 broadcast, W in LDS
//   * gather-aggregate: wave-per-node, lane = feature, 8x unrolled gathers
//   * self-loops analytic: out = relu(dinv*(hs[i]+sum hs[src])+b)
//   * mean-pool via per-graph binary search on sorted batch, then tiny FC
//   * ebuf aliases hs, ebuf2 aliases cur (build precedes layer compute)
// ---------------------------------------------------------------------------

#define RGRP 8
#define NSUB 512
#define SUB_PER 64   // NSUB / RGRP
#define MAXNODES 256 // >= ceil(N/NSUB); N=100k -> 196

__global__ void k_detect(const unsigned* __restrict__ ei, int* __restrict__ flag) {
  __shared__ int any;
  if (threadIdx.x == 0) any = 0;
  __syncthreads();
  unsigned v = 0;
  for (int i = threadIdx.x; i < 8192; i += blockDim.x) v |= ei[2 * i + 1];
  if (v) atomicOr(&any, 1);
  __syncthreads();
  if (threadIdx.x == 0) *flag = (any == 0) ? 1 : 0;  // 1 => int64 indices
}

__device__ __forceinline__ int load_idx(const void* p, long long i, bool wide) {
  if (wide) {
    long long v = __builtin_nontemporal_load((const long long*)p + i);
    return (int)v;
  }
  return __builtin_nontemporal_load((const int*)p + i);
}

// histogram: atomics spread over N counters (0.4MB)
__global__ void k_deg(const void* __restrict__ ei, int E, const int* __restrict__ flag,
                      int* __restrict__ deg) {
  const bool wide = (*flag != 0);
  for (int e = blockIdx.x * blockDim.x + threadIdx.x; e < E; e += gridDim.x * blockDim.x) {
    const int d = load_idx(ei, (long long)E + e, wide);
    atomicAdd(&deg[d], 1);
  }
}

__global__ void k_dinv(const int* __restrict__ deg, float* __restrict__ dinv, int N) {
  int i = blockIdx.x * blockDim.x + threadIdx.x;
  if (i < N) dinv[i] = rsqrtf((float)(deg[i] + 1));  // +1 self loop
}

// ---- exclusive scan of deg[N] -> rowptr[N+1], 2048 items/block -------------
__global__ void k_scan_a(const int* __restrict__ deg, int N, int* __restrict__ bsum) {
  __shared__ int sh[256];
  int base = blockIdx.x * 2048;
  int s = 0;
  for (int i = threadIdx.x; i < 2048; i += 256) {
    int idx = base + i;
    s += (idx < N) ? deg[idx] : 0;
  }
  sh[threadIdx.x] = s;
  __syncthreads();
  for (int off = 128; off > 0; off >>= 1) {
    if (threadIdx.x < off) sh[threadIdx.x] += sh[threadIdx.x + off];
    __syncthreads();
  }
  if (threadIdx.x == 0) bsum[blockIdx.x] = sh[0];
}

__global__ void k_scan_b(int* __restrict__ bsum, int nb) {
  if (threadIdx.x == 0) {
    int run = 0;
    for (int i = 0; i < nb; ++i) { int v = bsum[i]; bsum[i] = run; run += v; }
    bsum[nb] = run;
  }
}

__global__ void k_scan_c(const int* __restrict__ deg, int N, const int* __restrict__ bsum,
                         int* __restrict__ rowptr, int nb) {
  __shared__ int sh[256];
  int base = blockIdx.x * 2048;
  int v[8];
  int s = 0;
#pragma unroll
  for (int j = 0; j < 8; ++j) {
    int idx = base + threadIdx.x * 8 + j;
    v[j] = (idx < N) ? deg[idx] : 0;
    s += v[j];
  }
  sh[threadIdx.x] = s;
  __syncthreads();
  for (int off = 1; off < 256; off <<= 1) {
    int t = (threadIdx.x >= off) ? sh[threadIdx.x - off] : 0;
    __syncthreads();
    sh[threadIdx.x] += t;
    __syncthreads();
  }
  int excl = (threadIdx.x ? sh[threadIdx.x - 1] : 0) + bsum[blockIdx.x];
#pragma unroll
  for (int j = 0; j < 8; ++j) {
    int idx = base + threadIdx.x * 8 + j;
    if (idx < N) rowptr[idx] = excl;
    excl += v[j];
  }
  if (blockIdx.x == gridDim.x - 1 && threadIdx.x == 255) rowptr[N] = bsum[nb];
}

// rb[r] = rowptr[first node of range r]; sb[s] = rowptr[first node of sub s]
__global__ void k_bases(const int* __restrict__ rowptr, int* __restrict__ rb,
                        int* __restrict__ sb, int N) {
  int t = blockIdx.x * blockDim.x + threadIdx.x;
  if (t <= NSUB) {
    long long lo = ((long long)N * t + NSUB - 1) / NSUB;
    if (lo > N) lo = N;
    sb[t] = rowptr[lo];
  }
  if (t <= RGRP) {
    long long lo = ((long long)N * t + RGRP - 1) / RGRP;
    if (lo > N) lo = N;
    rb[t] = rowptr[lo];
  }
}

// p1: per-block chunk -> count 8 ranges in LDS, reserve, dense pair writes
__global__ __launch_bounds__(256) void k_bucket(const void* __restrict__ ei, int E,
                                                const int* __restrict__ flag,
                                                const int* __restrict__ rb,
                                                int* __restrict__ bcur,
                                                long long* __restrict__ ebuf, int N) {
  __shared__ int sh_cnt[RGRP];
  __shared__ int sh_base[RGRP];
  __shared__ int sh_off[RGRP];
  const bool wide = (*flag != 0);
  const int chunk = (E + gridDim.x - 1) / gridDim.x;
  const int c0 = blockIdx.x * chunk;
  const int c1 = (c0 + chunk < E) ? c0 + chunk : E;
  if (threadIdx.x < RGRP) { sh_cnt[threadIdx.x] = 0; sh_off[threadIdx.x] = 0; }
  __syncthreads();
  for (int e = c0 + threadIdx.x; e < c1; e += 256) {
    const int d = load_idx(ei, (long long)E + e, wide);
    const int r = (int)(((long long)d * RGRP) / N);
    atomicAdd(&sh_cnt[r], 1);
  }
  __syncthreads();
  if (threadIdx.x < RGRP)
    sh_base[threadIdx.x] = atomicAdd(&bcur[threadIdx.x], sh_cnt[threadIdx.x]);
  __syncthreads();
  for (int e = c0 + threadIdx.x; e < c1; e += 256) {
    const int d = load_idx(ei, (long long)E + e, wide);
    const int s = load_idx(ei, e, wide);
    const int r = (int)(((long long)d * RGRP) / N);
    const int o = atomicAdd(&sh_off[r], 1);
    const long long pos = (long long)rb[r] + sh_base[r] + o;
    ebuf[pos] = ((long long)(unsigned)d << 32) | (unsigned)s;
  }
}

// p2: range bucket -> 64 sub-buckets, exact rowptr-based slices (sb)
__global__ __launch_bounds__(256) void k_bucket2(const long long* __restrict__ ebuf,
                                                 const int* __restrict__ rb,
                                                 const int* __restrict__ sb,
                                                 int* __restrict__ scur,
                                                 long long* __restrict__ ebuf2, int N) {
  __shared__ int cnt[SUB_PER];
  __shared__ int base[SUB_PER];
  __shared__ int off[SUB_PER];
  const int r = blockIdx.x & (RGRP - 1);
  const int cb = blockIdx.x >> 3;
  const int nch = gridDim.x >> 3;
  const int e0 = rb[r], e1 = rb[r + 1];
  const int chunk = (e1 - e0 + nch - 1) / nch;
  const int c0 = e0 + cb * chunk;
  const int c1 = (c0 + chunk < e1) ? c0 + chunk : e1;
  if (threadIdx.x < SUB_PER) { cnt[threadIdx.x] = 0; off[threadIdx.x] = 0; }
  __syncthreads();
  for (int e = c0 + threadIdx.x; e < c1; e += 256) {
    const int d = (int)(ebuf[e] >> 32);
    const int ls = (int)(((long long)d * NSUB) / N) - r * SUB_PER;
    atomicAdd(&cnt[ls], 1);
  }
  __syncthreads();
  if (threadIdx.x < SUB_PER) {
    const int s = r * SUB_PER + threadIdx.x;
    base[threadIdx.x] = sb[s] + atomicAdd(&scur[s], cnt[threadIdx.x]);
  }
  __syncthreads();
  for (int e = c0 + threadIdx.x; e < c1; e += 256) {
    const long long v = ebuf[e];
    const int d = (int)(v >> 32);
    const int ls = (int)(((long long)d * NSUB) / N) - r * SUB_PER;
    const int o = atomicAdd(&off[ls], 1);
    ebuf2[base[ls] + o] = v;
  }
}

// p3: block-per-sub-bucket; LDS cursors start at rowptr[d]; csr region
// [rowptr[nlo], rowptr[nhi]) is written exclusively by this block (dense)
__global__ __launch_bounds__(256) void k_csr(const long long* __restrict__ ebuf2,
                                             const int* __restrict__ sb,
                                             const int* __restrict__ rowptr,
                                             int* __restrict__ csr, int N) {
  __shared__ int lcur[MAXNODES];
  const int s = blockIdx.x;
  int nlo = (int)(((long long)N * s + NSUB - 1) / NSUB);
  int nhi = (int)(((long long)N * (s + 1) + NSUB - 1) / NSUB);
  if (nhi > N) nhi = N;
  const int nn = nhi - nlo;
  for (int i = threadIdx.x; i < nn; i += 256) lcur[i] = rowptr[nlo + i];
  __syncthreads();
  const int e0 = sb[s], e1 = sb[s + 1];
  for (int e = e0 + threadIdx.x; e < e1; e += 256) {
    const long long v = __builtin_nontemporal_load(&ebuf2[e]);
    const int d = (int)(v >> 32);
    const int pos = atomicAdd(&lcur[d - nlo], 1);
    csr[pos] = (int)v;
  }
}

// ---- hs = dinv * (X @ W) ---------------------------------------------------
template <int K>
__global__ __launch_bounds__(256) void k_gemm_hs(const float* __restrict__ X,
                                                 const float* __restrict__ W,
                                                 const float* __restrict__ dinv,
                                                 float* __restrict__ HS, int N) {
  __shared__ float Wl[K * 64];
  __shared__ float Xl[64 * 32];
  for (int i = threadIdx.x; i < K * 64; i += 256) Wl[i] = W[i];
  const int col = threadIdx.x & 63;
  const int rw = threadIdx.x >> 6;
  const int srow = threadIdx.x >> 3;       // 0..31 staging row
  const int scol = (threadIdx.x & 7) * 4;  // 0,4,...,28 staging col

  const long long r0 = (long long)blockIdx.x * 64;
  const int rows = (int)((N - r0) < 64 ? (N - r0) : 64);

  float acc[16];
#pragma unroll
  for (int r = 0; r < 16; ++r) acc[r] = 0.f;

  for (int k0 = 0; k0 < K; k0 += 32) {
    __syncthreads();
#pragma unroll
    for (int p = 0; p < 2; ++p) {
      const int row = srow + p * 32;
      const int src = (row < rows) ? row : 0;  // safe tail source
      const float4 v = *(const float4*)&X[(r0 + src) * K + k0 + scol];
      *(float4*)&Xl[row * 32 + scol] = v;
    }
    __syncthreads();
#pragma unroll
    for (int kk = 0; kk < 32; kk += 4) {
      const float w0 = Wl[(k0 + kk + 0) * 64 + col];
      const float w1 = Wl[(k0 + kk + 1) * 64 + col];
      const float w2 = Wl[(k0 + kk + 2) * 64 + col];
      const float w3 = Wl[(k0 + kk + 3) * 64 + col];
#pragma unroll
      for (int r = 0; r < 16; ++r) {
        const float4 xv = *(const float4*)&Xl[(r * 4 + rw) * 32 + kk];
        acc[r] = fmaf(xv.w, w3, fmaf(xv.z, w2, fmaf(xv.y, w1, fmaf(xv.x, w0, acc[r]))));
      }
    }
  }
#pragma unroll
  for (int r = 0; r < 16; ++r) {
    const int lr = r * 4 + rw;
    if (lr < rows) {
      const long long row = r0 + lr;
      HS[row * 64 + col] = dinv[row] * acc[r];
    }
  }
}

// ---- out[i] = relu(dinv[i]*(hs[i] + sum_{src in(i)} hs[src]) + b) ----------
__global__ void k_agg(const float* __restrict__ HS, const int* __restrict__ rowptr,
                      const int* __restrict__ csr, const float* __restrict__ dinv,
                      const float* __restrict__ bias, float* __restrict__ OUT, int N) {
  const int lane = threadIdx.x & 63;
  const int wid = threadIdx.x >> 6;
  const int wavesPerBlock = blockDim.x >> 6;
  const float b = bias[lane];
  for (int node = blockIdx.x * wavesPerBlock + wid; node < N;
       node += wavesPerBlock * gridDim.x) {
    const int s0 = rowptr[node], s1 = rowptr[node + 1];
    float a0 = HS[(long long)node * 64 + lane];  // self loop
    float a1 = 0.f, a2 = 0.f, a3 = 0.f;
    for (int base = s0; base < s1; base += 64) {
      int m = s1 - base;
      if (m > 64) m = 64;
      const int idx = (base + lane < s1) ? csr[base + lane] : 0;
      int j = 0;
      for (; j + 8 <= m; j += 8) {
        const int i0 = __shfl(idx, j + 0, 64);
        const int i1 = __shfl(idx, j + 1, 64);
        const int i2 = __shfl(idx, j + 2, 64);
        const int i3 = __shfl(idx, j + 3, 64);
        const int i4 = __shfl(idx, j + 4, 64);
        const int i5 = __shfl(idx, j + 5, 64);
        const int i6 = __shfl(idx, j + 6, 64);
        const int i7 = __shfl(idx, j + 7, 64);
        const float v0 = HS[(long long)i0 * 64 + lane];
        const float v1 = HS[(long long)i1 * 64 + lane];
        const float v2 = HS[(long long)i2 * 64 + lane];
        const float v3 = HS[(long long)i3 * 64 + lane];
        const float v4 = HS[(long long)i4 * 64 + lane];
        const float v5 = HS[(long long)i5 * 64 + lane];
        const float v6 = HS[(long long)i6 * 64 + lane];
        const float v7 = HS[(long long)i7 * 64 + lane];
        a0 += v0 + v4;
        a1 += v1 + v5;
        a2 += v2 + v6;
        a3 += v3 + v7;
      }
      for (; j < m; ++j) {
        const int s = __shfl(idx, j, 64);
        a0 += HS[(long long)s * 64 + lane];
      }
    }
    OUT[(long long)node * 64 + lane] =
        fmaxf(fmaf(dinv[node], (a0 + a1) + (a2 + a3), b), 0.f);
  }
}

// ---- mean pool per graph (batch is sorted) ---------------------------------
__global__ void k_pool(const float* __restrict__ H, const void* __restrict__ batch,
                       const int* __restrict__ flag, float* __restrict__ pooled, int N) {
  __shared__ int se[2];
  __shared__ float red[4][64];
  bool wide = (*flag != 0);
  int g = blockIdx.x;
  if (threadIdx.x < 2) {
    int target = g + threadIdx.x;
    int lo = 0, hi = N;
    while (lo < hi) {
      int mid = (lo + hi) >> 1;
      long long v = wide ? ((const long long*)batch)[mid] : (long long)((const int*)batch)[mid];
      if (v < target) lo = mid + 1; else hi = mid;
    }
    se[threadIdx.x] = lo;
  }
  __syncthreads();
  int s = se[0], e = se[1];
  int lane = threadIdx.x & 63, wid = threadIdx.x >> 6;
  float acc = 0.f;
  for (int r = s + wid; r < e; r += 4) acc += H[(long long)r * 64 + lane];
  red[wid][lane] = acc;
  __syncthreads();
  if (wid == 0) {
    float v = red[0][lane] + red[1][lane] + red[2][lane] + red[3][lane];
    float cnt = (float)(e - s);
    pooled[g * 64 + lane] = v / fmaxf(cnt, 1.f);
  }
}

__global__ void k_classify(const float* __restrict__ pooled, const float* __restrict__ Wc,
                           const float* __restrict__ bc, float* __restrict__ out, int total) {
  int t = blockIdx.x * blockDim.x + threadIdx.x;
  if (t >= total) return;
  int g = t / 10, c = t % 10;
  float acc = bc[c];
#pragma unroll
  for (int h = 0; h < 64; ++h) acc += pooled[g * 64 + h] * Wc[h * 10 + c];
  out[t] = acc;
}

extern "C" void kernel_launch(void* const* d_in, const int* in_sizes, int n_in,
                              void* d_out, int out_size, void* d_ws, size_t ws_size,
                              hipStream_t stream) {
  const float* x = (const float*)d_in[0];
  const void* ei = d_in[1];
  const void* batch = d_in[2];
  const float* W1 = (const float*)d_in[3];
  const float* b1 = (const float*)d_in[4];
  const float* W2 = (const float*)d_in[5];
  const float* b2 = (const float*)d_in[6];
  const float* W3 = (const float*)d_in[7];
  const float* b3 = (const float*)d_in[8];
  const float* Wc = (const float*)d_in[9];
  const float* bc = (const float*)d_in[10];
  float* out = (float*)d_out;

  const int N = in_sizes[0] / 128;
  const int E = in_sizes[1] / 2;
  const int G = out_size / 10;
  const int NB = (N + 2047) / 2048;

  char* W = (char*)d_ws;
  size_t off = 0;
  auto take = [&](size_t b) -> void* {
    void* p = W + off;
    off += (b + 255) & ~(size_t)255;
    return p;
  };
  int* flag = (int*)take(4);
  int* deg = (int*)take((size_t)4 * N);
  int* rowptr = (int*)take((size_t)4 * (N + 1));
  int* bsum = (int*)take((size_t)4 * (NB + 1));
  int* rb = (int*)take((size_t)4 * (RGRP + 1));
  int* sb = (int*)take((size_t)4 * (NSUB + 1));
  int* bcur = (int*)take((size_t)4 * RGRP);
  int* scur = (int*)take((size_t)4 * NSUB);
  float* dinv = (float*)take((size_t)4 * N);
  int* csr = (int*)take((size_t)4 * E);
  // two big regions, time-shared: {ebuf -> hs}, {ebuf2 -> cur}
  const size_t bigBytes = ((size_t)8 * E > (size_t)4 * N * 64) ? (size_t)8 * E
                                                               : (size_t)4 * N * 64;
  void* big0 = take(bigBytes);
  void* big1 = take(bigBytes);
  float* pooled = (float*)take((size_t)4 * G * 64);
  (void)ws_size;

  long long* ebuf = (long long*)big0;
  long long* ebuf2 = (long long*)big1;
  float* hs = (float*)big0;
  float* cur = (float*)big1;

  hipMemsetAsync(deg, 0, (size_t)4 * N, stream);
  hipMemsetAsync(bcur, 0, (size_t)4 * RGRP, stream);
  hipMemsetAsync(scur, 0, (size_t)4 * NSUB, stream);

  k_detect<<<1, 256, 0, stream>>>((const unsigned*)ei, flag);
  k_deg<<<2048, 256, 0, stream>>>(ei, E, flag, deg);
  k_dinv<<<(N + 255) / 256, 256, 0, stream>>>(deg, dinv, N);
  k_scan_a<<<NB, 256, 0, stream>>>(deg, N, bsum);
  k_scan_b<<<1, 64, 0, stream>>>(bsum, NB);
  k_scan_c<<<NB, 256, 0, stream>>>(deg, N, bsum, rowptr, NB);
  k_bases<<<3, 256, 0, stream>>>(rowptr, rb, sb, N);
  k_bucket<<<1024, 256, 0, stream>>>(ei, E, flag, rb, bcur, ebuf, N);
  k_bucket2<<<256, 256, 0, stream>>>(ebuf, rb, sb, scur, ebuf2, N);
  k_csr<<<NSUB, 256, 0, stream>>>(ebuf2, sb, rowptr, csr, N);

  const int TILES = (N + 63) / 64;
  // layer 1: x[N,128] @ W1 -> hs; aggregate -> cur
  k_gemm_hs<128><<<TILES, 256, 0, stream>>>(x, W1, dinv, hs, N);
  k_agg<<<4096, 256, 0, stream>>>(hs, rowptr, csr, dinv, b1, cur, N);
  // layer 2
  k_gemm_hs<64><<<TILES, 256, 0, stream>>>(cur, W2, dinv, hs, N);
  k_agg<<<4096, 256, 0, stream>>>(hs, rowptr, csr, dinv, b2, cur, N);
  // layer 3
  k_gemm_hs<64><<<TILES, 256, 0, stream>>>(cur, W3, dinv, hs, N);
  k_agg<<<4096, 256, 0, stream>>>(hs, rowptr, csr, dinv, b3, cur, N);

  k_pool<<<G, 256, 0, stream>>>(cur, batch, flag, pooled, N);
  k_classify<<<(G * 10 + 255) / 256, 256, 0, stream>>>(pooled, Wc, bc, out, G * 10);
}

// Round 7
// 664.618 us; speedup vs baseline: 1.2766x; 1.1869x over previous
//
#include <hip/hip_runtime.h>

// ---------------------------------------------------------------------------
// MalwareGNN: 3-layer GCN (transform -> normalized aggregate) + mean pool + FC
//   * detect int32 vs int64 indices on device (flag in ws)
//   * CSR build, NO global-atomic histograms, NO write amplification:
//       p1 k_bucket : 8 capacity-sliced range buckets of (dst,src) pairs
//                     (count in LDS -> reserve slice, 8 atomics/block -> dense)
//       p2 k_bucket2: each range -> 64 capacity-sliced sub-buckets (512 total)
//       p3 k_subdeg : block-per-sub-bucket LDS histogram -> DENSE deg writes
//       scan        : deg -> rowptr
//       p4 k_csr    : block-per-sub-bucket, LDS cursors = rowptr[d], writes a
//                     contiguous ~25KB csr region exclusively owned by block
//   * per layer: GEMM hs = dinv*(X@W): 64-row tile, X staged in LDS k-chunks,
//     wave-uniform ds_read_b128 broadcast, W in LDS
//   * gather-aggregate: wave-per-node, lane = feature, 8x unrolled gathers
//   * self-loops analytic: out = relu(dinv*(hs[i]+sum hs[src])+b)
//   * mean-pool via per-graph binary search on sorted batch, then tiny FC
//   * ebuf aliases hs, ebuf2 aliases cur (build precedes layer compute)
// ---------------------------------------------------------------------------

#define RGRP 8
#define NSUB 512
#define SUB_PER 64   // NSUB / RGRP
#define MAXNODES 256 // >= ceil(N/NSUB); N=100k -> 196

__global__ void k_detect(const unsigned* __restrict__ ei, int* __restrict__ flag) {
  __shared__ int any;
  if (threadIdx.x == 0) any = 0;
  __syncthreads();
  unsigned v = 0;
  for (int i = threadIdx.x; i < 8192; i += blockDim.x) v |= ei[2 * i + 1];
  if (v) atomicOr(&any, 1);
  __syncthreads();
  if (threadIdx.x == 0) *flag = (any == 0) ? 1 : 0;  // 1 => int64 indices
}

__device__ __forceinline__ int load_idx(const void* p, long long i, bool wide) {
  if (wide) {
    long long v = __builtin_nontemporal_load((const long long*)p + i);
    return (int)v;
  }
  return __builtin_nontemporal_load((const int*)p + i);
}

// p1: per-block chunk -> count 8 ranges in LDS, reserve, dense pair writes
__global__ __launch_bounds__(256) void k_bucket(const void* __restrict__ ei, int E,
                                                const int* __restrict__ flag,
                                                int cap1, int* __restrict__ bcur,
                                                long long* __restrict__ ebuf, int N) {
  __shared__ int sh_cnt[RGRP];
  __shared__ int sh_base[RGRP];
  __shared__ int sh_off[RGRP];
  const bool wide = (*flag != 0);
  const int chunk = (E + gridDim.x - 1) / gridDim.x;
  const int c0 = blockIdx.x * chunk;
  const int c1 = (c0 + chunk < E) ? c0 + chunk : E;
  if (threadIdx.x < RGRP) { sh_cnt[threadIdx.x] = 0; sh_off[threadIdx.x] = 0; }
  __syncthreads();
  for (int e = c0 + threadIdx.x; e < c1; e += 256) {
    const int d = load_idx(ei, (long long)E + e, wide);
    const int r = (int)(((long long)d * RGRP) / N);
    atomicAdd(&sh_cnt[r], 1);
  }
  __syncthreads();
  if (threadIdx.x < RGRP)
    sh_base[threadIdx.x] = atomicAdd(&bcur[threadIdx.x], sh_cnt[threadIdx.x]);
  __syncthreads();
  const long long cap = (long long)RGRP * cap1;
  for (int e = c0 + threadIdx.x; e < c1; e += 256) {
    const int d = load_idx(ei, (long long)E + e, wide);
    const int s = load_idx(ei, e, wide);
    const int r = (int)(((long long)d * RGRP) / N);
    const int o = atomicAdd(&sh_off[r], 1);
    long long pos = (long long)r * cap1 + sh_base[r] + o;
    if (pos >= cap) pos = cap - 1;  // paranoia clamp (slack makes this dead)
    ebuf[pos] = ((long long)(unsigned)d << 32) | (unsigned)s;
  }
}

// p2: range bucket -> 64 capacity-sliced sub-buckets
__global__ __launch_bounds__(256) void k_bucket2(const long long* __restrict__ ebuf,
                                                 const int* __restrict__ bcur,
                                                 int cap1, int cap2,
                                                 int* __restrict__ scur,
                                                 long long* __restrict__ ebuf2, int N) {
  __shared__ int cnt[SUB_PER];
  __shared__ int base[SUB_PER];
  __shared__ int off[SUB_PER];
  const int r = blockIdx.x & (RGRP - 1);
  const int cb = blockIdx.x >> 3;
  const int nch = gridDim.x >> 3;
  const long long e0 = (long long)r * cap1;
  const long long e1 = e0 + bcur[r];
  const int total = (int)(e1 - e0);
  const int chunk = (total + nch - 1) / nch;
  const long long c0 = e0 + (long long)cb * chunk;
  long long c1 = c0 + chunk;
  if (c1 > e1) c1 = e1;
  if (threadIdx.x < SUB_PER) { cnt[threadIdx.x] = 0; off[threadIdx.x] = 0; }
  __syncthreads();
  for (long long e = c0 + threadIdx.x; e < c1; e += 256) {
    const int d = (int)(ebuf[e] >> 32);
    const int ls = (int)(((long long)d * NSUB) / N) - r * SUB_PER;
    atomicAdd(&cnt[ls], 1);
  }
  __syncthreads();
  if (threadIdx.x < SUB_PER) {
    const int s = r * SUB_PER + threadIdx.x;
    base[threadIdx.x] = atomicAdd(&scur[s], cnt[threadIdx.x]);
  }
  __syncthreads();
  const long long cap = (long long)NSUB * cap2;
  for (long long e = c0 + threadIdx.x; e < c1; e += 256) {
    const long long v = ebuf[e];
    const int d = (int)(v >> 32);
    const int ls = (int)(((long long)d * NSUB) / N) - r * SUB_PER;
    const int o = atomicAdd(&off[ls], 1);
    long long pos = (long long)(r * SUB_PER + ls) * cap2 + base[ls] + o;
    if (pos >= cap) pos = cap - 1;  // paranoia clamp
    ebuf2[pos] = v;
  }
}

// p3: per-sub-bucket LDS histogram -> dense deg writes (no global atomics)
__global__ __launch_bounds__(256) void k_subdeg(const long long* __restrict__ ebuf2,
                                                const int* __restrict__ scur, int cap2,
                                                int* __restrict__ deg, int N) {
  __shared__ int hist[MAXNODES];
  const int s = blockIdx.x;
  int nlo = (int)(((long long)N * s + NSUB - 1) / NSUB);
  int nhi = (int)(((long long)N * (s + 1) + NSUB - 1) / NSUB);
  if (nhi > N) nhi = N;
  const int nn = nhi - nlo;
  for (int i = threadIdx.x; i < nn; i += 256) hist[i] = 0;
  __syncthreads();
  const long long e0 = (long long)s * cap2;
  const long long e1 = e0 + scur[s];
  for (long long e = e0 + threadIdx.x; e < e1; e += 256) {
    const int d = (int)(__builtin_nontemporal_load(&ebuf2[e]) >> 32);
    atomicAdd(&hist[d - nlo], 1);
  }
  __syncthreads();
  for (int i = threadIdx.x; i < nn; i += 256) deg[nlo + i] = hist[i];
}

__global__ void k_dinv(const int* __restrict__ deg, float* __restrict__ dinv, int N) {
  int i = blockIdx.x * blockDim.x + threadIdx.x;
  if (i < N) dinv[i] = rsqrtf((float)(deg[i] + 1));  // +1 self loop
}

// ---- exclusive scan of deg[N] -> rowptr[N+1], 2048 items/block -------------
__global__ void k_scan_a(const int* __restrict__ deg, int N, int* __restrict__ bsum) {
  __shared__ int sh[256];
  int base = blockIdx.x * 2048;
  int s = 0;
  for (int i = threadIdx.x; i < 2048; i += 256) {
    int idx = base + i;
    s += (idx < N) ? deg[idx] : 0;
  }
  sh[threadIdx.x] = s;
  __syncthreads();
  for (int off = 128; off > 0; off >>= 1) {
    if (threadIdx.x < off) sh[threadIdx.x] += sh[threadIdx.x + off];
    __syncthreads();
  }
  if (threadIdx.x == 0) bsum[blockIdx.x] = sh[0];
}

__global__ void k_scan_b(int* __restrict__ bsum, int nb) {
  if (threadIdx.x == 0) {
    int run = 0;
    for (int i = 0; i < nb; ++i) { int v = bsum[i]; bsum[i] = run; run += v; }
    bsum[nb] = run;
  }
}

__global__ void k_scan_c(const int* __restrict__ deg, int N, const int* __restrict__ bsum,
                         int* __restrict__ rowptr, int nb) {
  __shared__ int sh[256];
  int base = blockIdx.x * 2048;
  int v[8];
  int s = 0;
#pragma unroll
  for (int j = 0; j < 8; ++j) {
    int idx = base + threadIdx.x * 8 + j;
    v[j] = (idx < N) ? deg[idx] : 0;
    s += v[j];
  }
  sh[threadIdx.x] = s;
  __syncthreads();
  for (int off = 1; off < 256; off <<= 1) {
    int t = (threadIdx.x >= off) ? sh[threadIdx.x - off] : 0;
    __syncthreads();
    sh[threadIdx.x] += t;
    __syncthreads();
  }
  int excl = (threadIdx.x ? sh[threadIdx.x - 1] : 0) + bsum[blockIdx.x];
#pragma unroll
  for (int j = 0; j < 8; ++j) {
    int idx = base + threadIdx.x * 8 + j;
    if (idx < N) rowptr[idx] = excl;
    excl += v[j];
  }
  if (blockIdx.x == gridDim.x - 1 && threadIdx.x == 255) rowptr[N] = bsum[nb];
}

// p4: block-per-sub-bucket; LDS cursors start at rowptr[d]; csr region
// [rowptr[nlo], rowptr[nhi]) is written exclusively by this block (dense)
__global__ __launch_bounds__(256) void k_csr(const long long* __restrict__ ebuf2,
                                             const int* __restrict__ scur, int cap2,
                                             const int* __restrict__ rowptr,
                                             int* __restrict__ csr, int N) {
  __shared__ int lcur[MAXNODES];
  const int s = blockIdx.x;
  int nlo = (int)(((long long)N * s + NSUB - 1) / NSUB);
  int nhi = (int)(((long long)N * (s + 1) + NSUB - 1) / NSUB);
  if (nhi > N) nhi = N;
  const int nn = nhi - nlo;
  for (int i = threadIdx.x; i < nn; i += 256) lcur[i] = rowptr[nlo + i];
  __syncthreads();
  const long long e0 = (long long)s * cap2;
  const long long e1 = e0 + scur[s];
  for (long long e = e0 + threadIdx.x; e < e1; e += 256) {
    const long long v = __builtin_nontemporal_load(&ebuf2[e]);
    const int d = (int)(v >> 32);
    const int pos = atomicAdd(&lcur[d - nlo], 1);
    csr[pos] = (int)v;
  }
}

// ---- hs = dinv * (X @ W) ---------------------------------------------------
template <int K>
__global__ __launch_bounds__(256) void k_gemm_hs(const float* __restrict__ X,
                                                 const float* __restrict__ W,
                                                 const float* __restrict__ dinv,
                                                 float* __restrict__ HS, int N) {
  __shared__ float Wl[K * 64];
  __shared__ float Xl[64 * 32];
  for (int i = threadIdx.x; i < K * 64; i += 256) Wl[i] = W[i];
  const int col = threadIdx.x & 63;
  const int rw = threadIdx.x >> 6;
  const int srow = threadIdx.x >> 3;       // 0..31 staging row
  const int scol = (threadIdx.x & 7) * 4;  // 0,4,...,28 staging col

  const long long r0 = (long long)blockIdx.x * 64;
  const int rows = (int)((N - r0) < 64 ? (N - r0) : 64);

  float acc[16];
#pragma unroll
  for (int r = 0; r < 16; ++r) acc[r] = 0.f;

  for (int k0 = 0; k0 < K; k0 += 32) {
    __syncthreads();
#pragma unroll
    for (int p = 0; p < 2; ++p) {
      const int row = srow + p * 32;
      const int src = (row < rows) ? row : 0;  // safe tail source
      const float4 v = *(const float4*)&X[(r0 + src) * K + k0 + scol];
      *(float4*)&Xl[row * 32 + scol] = v;
    }
    __syncthreads();
#pragma unroll
    for (int kk = 0; kk < 32; kk += 4) {
      const float w0 = Wl[(k0 + kk + 0) * 64 + col];
      const float w1 = Wl[(k0 + kk + 1) * 64 + col];
      const float w2 = Wl[(k0 + kk + 2) * 64 + col];
      const float w3 = Wl[(k0 + kk + 3) * 64 + col];
#pragma unroll
      for (int r = 0; r < 16; ++r) {
        const float4 xv = *(const float4*)&Xl[(r * 4 + rw) * 32 + kk];
        acc[r] = fmaf(xv.w, w3, fmaf(xv.z, w2, fmaf(xv.y, w1, fmaf(xv.x, w0, acc[r]))));
      }
    }
  }
#pragma unroll
  for (int r = 0; r < 16; ++r) {
    const int lr = r * 4 + rw;
    if (lr < rows) {
      const long long row = r0 + lr;
      HS[row * 64 + col] = dinv[row] * acc[r];
    }
  }
}

// ---- out[i] = relu(dinv[i]*(hs[i] + sum_{src in(i)} hs[src]) + b) ----------
__global__ void k_agg(const float* __restrict__ HS, const int* __restrict__ rowptr,
                      const int* __restrict__ csr, const float* __restrict__ dinv,
                      const float* __restrict__ bias, float* __restrict__ OUT, int N) {
  const int lane = threadIdx.x & 63;
  const int wid = threadIdx.x >> 6;
  const int wavesPerBlock = blockDim.x >> 6;
  const float b = bias[lane];
  for (int node = blockIdx.x * wavesPerBlock + wid; node < N;
       node += wavesPerBlock * gridDim.x) {
    const int s0 = rowptr[node], s1 = rowptr[node + 1];
    float a0 = HS[(long long)node * 64 + lane];  // self loop
    float a1 = 0.f, a2 = 0.f, a3 = 0.f;
    for (int base = s0; base < s1; base += 64) {
      int m = s1 - base;
      if (m > 64) m = 64;
      const int idx = (base + lane < s1) ? csr[base + lane] : 0;
      int j = 0;
      for (; j + 8 <= m; j += 8) {
        const int i0 = __shfl(idx, j + 0, 64);
        const int i1 = __shfl(idx, j + 1, 64);
        const int i2 = __shfl(idx, j + 2, 64);
        const int i3 = __shfl(idx, j + 3, 64);
        const int i4 = __shfl(idx, j + 4, 64);
        const int i5 = __shfl(idx, j + 5, 64);
        const int i6 = __shfl(idx, j + 6, 64);
        const int i7 = __shfl(idx, j + 7, 64);
        const float v0 = HS[(long long)i0 * 64 + lane];
        const float v1 = HS[(long long)i1 * 64 + lane];
        const float v2 = HS[(long long)i2 * 64 + lane];
        const float v3 = HS[(long long)i3 * 64 + lane];
        const float v4 = HS[(long long)i4 * 64 + lane];
        const float v5 = HS[(long long)i5 * 64 + lane];
        const float v6 = HS[(long long)i6 * 64 + lane];
        const float v7 = HS[(long long)i7 * 64 + lane];
        a0 += v0 + v4;
        a1 += v1 + v5;
        a2 += v2 + v6;
        a3 += v3 + v7;
      }
      for (; j < m; ++j) {
        const int s = __shfl(idx, j, 64);
        a0 += HS[(long long)s * 64 + lane];
      }
    }
    OUT[(long long)node * 64 + lane] =
        fmaxf(fmaf(dinv[node], (a0 + a1) + (a2 + a3), b), 0.f);
  }
}

// ---- mean pool per graph (batch is sorted) ---------------------------------
__global__ void k_pool(const float* __restrict__ H, const void* __restrict__ batch,
                       const int* __restrict__ flag, float* __restrict__ pooled, int N) {
  __shared__ int se[2];
  __shared__ float red[4][64];
  bool wide = (*flag != 0);
  int g = blockIdx.x;
  if (threadIdx.x < 2) {
    int target = g + threadIdx.x;
    int lo = 0, hi = N;
    while (lo < hi) {
      int mid = (lo + hi) >> 1;
      long long v = wide ? ((const long long*)batch)[mid] : (long long)((const int*)batch)[mid];
      if (v < target) lo = mid + 1; else hi = mid;
    }
    se[threadIdx.x] = lo;
  }
  __syncthreads();
  int s = se[0], e = se[1];
  int lane = threadIdx.x & 63, wid = threadIdx.x >> 6;
  float acc = 0.f;
  for (int r = s + wid; r < e; r += 4) acc += H[(long long)r * 64 + lane];
  red[wid][lane] = acc;
  __syncthreads();
  if (wid == 0) {
    float v = red[0][lane] + red[1][lane] + red[2][lane] + red[3][lane];
    float cnt = (float)(e - s);
    pooled[g * 64 + lane] = v / fmaxf(cnt, 1.f);
  }
}

__global__ void k_classify(const float* __restrict__ pooled, const float* __restrict__ Wc,
                           const float* __restrict__ bc, float* __restrict__ out, int total) {
  int t = blockIdx.x * blockDim.x + threadIdx.x;
  if (t >= total) return;
  int g = t / 10, c = t % 10;
  float acc = bc[c];
#pragma unroll
  for (int h = 0; h < 64; ++h) acc += pooled[g * 64 + h] * Wc[h * 10 + c];
  out[t] = acc;
}

extern "C" void kernel_launch(void* const* d_in, const int* in_sizes, int n_in,
                              void* d_out, int out_size, void* d_ws, size_t ws_size,
                              hipStream_t stream) {
  const float* x = (const float*)d_in[0];
  const void* ei = d_in[1];
  const void* batch = d_in[2];
  const float* W1 = (const float*)d_in[3];
  const float* b1 = (const float*)d_in[4];
  const float* W2 = (const float*)d_in[5];
  const float* b2 = (const float*)d_in[6];
  const float* W3 = (const float*)d_in[7];
  const float* b3 = (const float*)d_in[8];
  const float* Wc = (const float*)d_in[9];
  const float* bc = (const float*)d_in[10];
  float* out = (float*)d_out;

  const int N = in_sizes[0] / 128;
  const int E = in_sizes[1] / 2;
  const int G = out_size / 10;
  const int NB = (N + 2047) / 2048;
  const int cap1 = E / RGRP + E / RGRP / 16 + 256;   // ~6% slack
  const int cap2 = E / NSUB + E / NSUB / 8 + 64;     // ~12.5% slack

  char* W = (char*)d_ws;
  size_t off = 0;
  auto take = [&](size_t b) -> void* {
    void* p = W + off;
    off += (b + 255) & ~(size_t)255;
    return p;
  };
  int* flag = (int*)take(4);
  int* deg = (int*)take((size_t)4 * N);
  int* rowptr = (int*)take((size_t)4 * (N + 1));
  int* bsum = (int*)take((size_t)4 * (NB + 1));
  int* bcur = (int*)take((size_t)4 * RGRP);
  int* scur = (int*)take((size_t)4 * NSUB);
  float* dinv = (float*)take((size_t)4 * N);
  int* csr = (int*)take((size_t)4 * E);
  // two big regions, time-shared: {ebuf -> hs}, {ebuf2 -> cur}
  size_t bigBytes = (size_t)8 * RGRP * cap1;
  if ((size_t)8 * NSUB * cap2 > bigBytes) bigBytes = (size_t)8 * NSUB * cap2;
  if ((size_t)4 * N * 64 > bigBytes) bigBytes = (size_t)4 * N * 64;
  void* big0 = take(bigBytes);
  void* big1 = take(bigBytes);
  float* pooled = (float*)take((size_t)4 * G * 64);
  (void)ws_size;

  long long* ebuf = (long long*)big0;
  long long* ebuf2 = (long long*)big1;
  float* hs = (float*)big0;
  float* cur = (float*)big1;

  hipMemsetAsync(bcur, 0, (size_t)4 * RGRP, stream);
  hipMemsetAsync(scur, 0, (size_t)4 * NSUB, stream);

  k_detect<<<1, 256, 0, stream>>>((const unsigned*)ei, flag);
  k_bucket<<<1024, 256, 0, stream>>>(ei, E, flag, cap1, bcur, ebuf, N);
  k_bucket2<<<256, 256, 0, stream>>>(ebuf, bcur, cap1, cap2, scur, ebuf2, N);
  k_subdeg<<<NSUB, 256, 0, stream>>>(ebuf2, scur, cap2, deg, N);
  k_dinv<<<(N + 255) / 256, 256, 0, stream>>>(deg, dinv, N);
  k_scan_a<<<NB, 256, 0, stream>>>(deg, N, bsum);
  k_scan_b<<<1, 64, 0, stream>>>(bsum, NB);
  k_scan_c<<<NB, 256, 0, stream>>>(deg, N, bsum, rowptr, NB);
  k_csr<<<NSUB, 256, 0, stream>>>(ebuf2, scur, cap2, rowptr, csr, N);

  const int TILES = (N + 63) / 64;
  // layer 1: x[N,128] @ W1 -> hs; aggregate -> cur
  k_gemm_hs<128><<<TILES, 256, 0, stream>>>(x, W1, dinv, hs, N);
  k_agg<<<4096, 256, 0, stream>>>(hs, rowptr, csr, dinv, b1, cur, N);
  // layer 2
  k_gemm_hs<64><<<TILES, 256, 0, stream>>>(cur, W2, dinv, hs, N);
  k_agg<<<4096, 256, 0, stream>>>(hs, rowptr, csr, dinv, b2, cur, N);
  // layer 3
  k_gemm_hs<64><<<TILES, 256, 0, stream>>>(cur, W3, dinv, hs, N);
  k_agg<<<4096, 256, 0, stream>>>(hs, rowptr, csr, dinv, b3, cur, N);

  k_pool<<<G, 256, 0, stream>>>(cur, batch, flag, pooled, N);
  k_classify<<<(G * 10 + 255) / 256, 256, 0, stream>>>(pooled, Wc, bc, out, G * 10);
}

// Round 8
// 539.843 us; speedup vs baseline: 1.5716x; 1.2311x over previous
//
#include <hip/hip_runtime.h>

// ---------------------------------------------------------------------------
// MalwareGNN: 3-layer GCN (transform -> normalized aggregate) + mean pool + FC
//   * detect int32 vs int64 indices on device (flag in ws)
//   * CSR build, NO global-atomic histograms, NO write amplification:
//       p1 k_bucket : 8 capacity-sliced range buckets of (dst,src) pairs
//       p2 k_bucket2: each range -> 64 capacity-sliced sub-buckets (512 total)
//       p3 k_subdeg : block-per-sub-bucket LDS histogram -> DENSE deg writes
//       scan        : deg -> rowptr
//       p4 k_csr    : block-per-sub-bucket, LDS cursors = rowptr[d]
//   * per layer: GEMM hs = bf16(dinv*(X@W)) -- HS stored bf16 so the random
//     row-gather in k_agg moves 128B/row instead of 256B (L2-miss-bound)
//   * gather-aggregate: wave-per-node, lane = feature, 8x unrolled gathers,
//     f32 accumulate; layer outputs stay f32
//   * self-loops analytic: out = relu(dinv*(hs[i]+sum hs[src])+b)
//   * mean-pool via per-graph binary search on sorted batch, then tiny FC
//   * ebuf aliases hs region, ebuf2 aliases cur (build precedes compute)
// ---------------------------------------------------------------------------

#define RGRP 8
#define NSUB 512
#define SUB_PER 64   // NSUB / RGRP
#define MAXNODES 256 // >= ceil(N/NSUB); N=100k -> 196

__device__ __forceinline__ unsigned short f2bf(float x) {
  unsigned u = __float_as_uint(x);
  u += 0x7FFFu + ((u >> 16) & 1u);  // RNE
  return (unsigned short)(u >> 16);
}
__device__ __forceinline__ float bf2f(unsigned short h) {
  return __uint_as_float((unsigned)h << 16);
}

__global__ void k_detect(const unsigned* __restrict__ ei, int* __restrict__ flag) {
  __shared__ int any;
  if (threadIdx.x == 0) any = 0;
  __syncthreads();
  unsigned v = 0;
  for (int i = threadIdx.x; i < 8192; i += blockDim.x) v |= ei[2 * i + 1];
  if (v) atomicOr(&any, 1);
  __syncthreads();
  if (threadIdx.x == 0) *flag = (any == 0) ? 1 : 0;  // 1 => int64 indices
}

__device__ __forceinline__ int load_idx(const void* p, long long i, bool wide) {
  if (wide) {
    long long v = __builtin_nontemporal_load((const long long*)p + i);
    return (int)v;
  }
  return __builtin_nontemporal_load((const int*)p + i);
}

// p1: per-block chunk -> count 8 ranges in LDS, reserve, dense pair writes
__global__ __launch_bounds__(256) void k_bucket(const void* __restrict__ ei, int E,
                                                const int* __restrict__ flag,
                                                int cap1, int* __restrict__ bcur,
                                                long long* __restrict__ ebuf, int N) {
  __shared__ int sh_cnt[RGRP];
  __shared__ int sh_base[RGRP];
  __shared__ int sh_off[RGRP];
  const bool wide = (*flag != 0);
  const int chunk = (E + gridDim.x - 1) / gridDim.x;
  const int c0 = blockIdx.x * chunk;
  const int c1 = (c0 + chunk < E) ? c0 + chunk : E;
  if (threadIdx.x < RGRP) { sh_cnt[threadIdx.x] = 0; sh_off[threadIdx.x] = 0; }
  __syncthreads();
  for (int e = c0 + threadIdx.x; e < c1; e += 256) {
    const int d = load_idx(ei, (long long)E + e, wide);
    const int r = (int)(((long long)d * RGRP) / N);
    atomicAdd(&sh_cnt[r], 1);
  }
  __syncthreads();
  if (threadIdx.x < RGRP)
    sh_base[threadIdx.x] = atomicAdd(&bcur[threadIdx.x], sh_cnt[threadIdx.x]);
  __syncthreads();
  const long long cap = (long long)RGRP * cap1;
  for (int e = c0 + threadIdx.x; e < c1; e += 256) {
    const int d = load_idx(ei, (long long)E + e, wide);
    const int s = load_idx(ei, e, wide);
    const int r = (int)(((long long)d * RGRP) / N);
    const int o = atomicAdd(&sh_off[r], 1);
    long long pos = (long long)r * cap1 + sh_base[r] + o;
    if (pos >= cap) pos = cap - 1;  // paranoia clamp (slack makes this dead)
    ebuf[pos] = ((long long)(unsigned)d << 32) | (unsigned)s;
  }
}

// p2: range bucket -> 64 capacity-sliced sub-buckets
__global__ __launch_bounds__(256) void k_bucket2(const long long* __restrict__ ebuf,
                                                 const int* __restrict__ bcur,
                                                 int cap1, int cap2,
                                                 int* __restrict__ scur,
                                                 long long* __restrict__ ebuf2, int N) {
  __shared__ int cnt[SUB_PER];
  __shared__ int base[SUB_PER];
  __shared__ int off[SUB_PER];
  const int r = blockIdx.x & (RGRP - 1);
  const int cb = blockIdx.x >> 3;
  const int nch = gridDim.x >> 3;
  const long long e0 = (long long)r * cap1;
  const long long e1 = e0 + bcur[r];
  const int total = (int)(e1 - e0);
  const int chunk = (total + nch - 1) / nch;
  const long long c0 = e0 + (long long)cb * chunk;
  long long c1 = c0 + chunk;
  if (c1 > e1) c1 = e1;
  if (threadIdx.x < SUB_PER) { cnt[threadIdx.x] = 0; off[threadIdx.x] = 0; }
  __syncthreads();
  for (long long e = c0 + threadIdx.x; e < c1; e += 256) {
    const int d = (int)(ebuf[e] >> 32);
    const int ls = (int)(((long long)d * NSUB) / N) - r * SUB_PER;
    atomicAdd(&cnt[ls], 1);
  }
  __syncthreads();
  if (threadIdx.x < SUB_PER) {
    const int s = r * SUB_PER + threadIdx.x;
    base[threadIdx.x] = atomicAdd(&scur[s], cnt[threadIdx.x]);
  }
  __syncthreads();
  const long long cap = (long long)NSUB * cap2;
  for (long long e = c0 + threadIdx.x; e < c1; e += 256) {
    const long long v = ebuf[e];
    const int d = (int)(v >> 32);
    const int ls = (int)(((long long)d * NSUB) / N) - r * SUB_PER;
    const int o = atomicAdd(&off[ls], 1);
    long long pos = (long long)(r * SUB_PER + ls) * cap2 + base[ls] + o;
    if (pos >= cap) pos = cap - 1;  // paranoia clamp
    ebuf2[pos] = v;
  }
}

// p3: per-sub-bucket LDS histogram -> dense deg writes (no global atomics)
__global__ __launch_bounds__(256) void k_subdeg(const long long* __restrict__ ebuf2,
                                                const int* __restrict__ scur, int cap2,
                                                int* __restrict__ deg, int N) {
  __shared__ int hist[MAXNODES];
  const int s = blockIdx.x;
  int nlo = (int)(((long long)N * s + NSUB - 1) / NSUB);
  int nhi = (int)(((long long)N * (s + 1) + NSUB - 1) / NSUB);
  if (nhi > N) nhi = N;
  const int nn = nhi - nlo;
  for (int i = threadIdx.x; i < nn; i += 256) hist[i] = 0;
  __syncthreads();
  const long long e0 = (long long)s * cap2;
  const long long e1 = e0 + scur[s];
  for (long long e = e0 + threadIdx.x; e < e1; e += 256) {
    const int d = (int)(__builtin_nontemporal_load(&ebuf2[e]) >> 32);
    atomicAdd(&hist[d - nlo], 1);
  }
  __syncthreads();
  for (int i = threadIdx.x; i < nn; i += 256) deg[nlo + i] = hist[i];
}

__global__ void k_dinv(const int* __restrict__ deg, float* __restrict__ dinv, int N) {
  int i = blockIdx.x * blockDim.x + threadIdx.x;
  if (i < N) dinv[i] = rsqrtf((float)(deg[i] + 1));  // +1 self loop
}

// ---- exclusive scan of deg[N] -> rowptr[N+1], 2048 items/block -------------
__global__ void k_scan_a(const int* __restrict__ deg, int N, int* __restrict__ bsum) {
  __shared__ int sh[256];
  int base = blockIdx.x * 2048;
  int s = 0;
  for (int i = threadIdx.x; i < 2048; i += 256) {
    int idx = base + i;
    s += (idx < N) ? deg[idx] : 0;
  }
  sh[threadIdx.x] = s;
  __syncthreads();
  for (int off = 128; off > 0; off >>= 1) {
    if (threadIdx.x < off) sh[threadIdx.x] += sh[threadIdx.x + off];
    __syncthreads();
  }
  if (threadIdx.x == 0) bsum[blockIdx.x] = sh[0];
}

__global__ void k_scan_b(int* __restrict__ bsum, int nb) {
  if (threadIdx.x == 0) {
    int run = 0;
    for (int i = 0; i < nb; ++i) { int v = bsum[i]; bsum[i] = run; run += v; }
    bsum[nb] = run;
  }
}

__global__ void k_scan_c(const int* __restrict__ deg, int N, const int* __restrict__ bsum,
                         int* __restrict__ rowptr, int nb) {
  __shared__ int sh[256];
  int base = blockIdx.x * 2048;
  int v[8];
  int s = 0;
#pragma unroll
  for (int j = 0; j < 8; ++j) {
    int idx = base + threadIdx.x * 8 + j;
    v[j] = (idx < N) ? deg[idx] : 0;
    s += v[j];
  }
  sh[threadIdx.x] = s;
  __syncthreads();
  for (int off = 1; off < 256; off <<= 1) {
    int t = (threadIdx.x >= off) ? sh[threadIdx.x - off] : 0;
    __syncthreads();
    sh[threadIdx.x] += t;
    __syncthreads();
  }
  int excl = (threadIdx.x ? sh[threadIdx.x - 1] : 0) + bsum[blockIdx.x];
#pragma unroll
  for (int j = 0; j < 8; ++j) {
    int idx = base + threadIdx.x * 8 + j;
    if (idx < N) rowptr[idx] = excl;
    excl += v[j];
  }
  if (blockIdx.x == gridDim.x - 1 && threadIdx.x == 255) rowptr[N] = bsum[nb];
}

// p4: block-per-sub-bucket; LDS cursors start at rowptr[d]
__global__ __launch_bounds__(256) void k_csr(const long long* __restrict__ ebuf2,
                                             const int* __restrict__ scur, int cap2,
                                             const int* __restrict__ rowptr,
                                             int* __restrict__ csr, int N) {
  __shared__ int lcur[MAXNODES];
  const int s = blockIdx.x;
  int nlo = (int)(((long long)N * s + NSUB - 1) / NSUB);
  int nhi = (int)(((long long)N * (s + 1) + NSUB - 1) / NSUB);
  if (nhi > N) nhi = N;
  const int nn = nhi - nlo;
  for (int i = threadIdx.x; i < nn; i += 256) lcur[i] = rowptr[nlo + i];
  __syncthreads();
  const long long e0 = (long long)s * cap2;
  const long long e1 = e0 + scur[s];
  for (long long e = e0 + threadIdx.x; e < e1; e += 256) {
    const long long v = __builtin_nontemporal_load(&ebuf2[e]);
    const int d = (int)(v >> 32);
    const int pos = atomicAdd(&lcur[d - nlo], 1);
    csr[pos] = (int)v;
  }
}

// ---- HS = bf16(dinv * (X @ W)) ---------------------------------------------
template <int K>
__global__ __launch_bounds__(256) void k_gemm_hs(const float* __restrict__ X,
                                                 const float* __restrict__ W,
                                                 const float* __restrict__ dinv,
                                                 unsigned short* __restrict__ HS, int N) {
  __shared__ float Wl[K * 64];
  __shared__ float Xl[64 * 32];
  for (int i = threadIdx.x; i < K * 64; i += 256) Wl[i] = W[i];
  const int col = threadIdx.x & 63;
  const int rw = threadIdx.x >> 6;
  const int srow = threadIdx.x >> 3;       // 0..31 staging row
  const int scol = (threadIdx.x & 7) * 4;  // 0,4,...,28 staging col

  const long long r0 = (long long)blockIdx.x * 64;
  const int rows = (int)((N - r0) < 64 ? (N - r0) : 64);

  float acc[16];
#pragma unroll
  for (int r = 0; r < 16; ++r) acc[r] = 0.f;

  for (int k0 = 0; k0 < K; k0 += 32) {
    __syncthreads();
#pragma unroll
    for (int p = 0; p < 2; ++p) {
      const int row = srow + p * 32;
      const int src = (row < rows) ? row : 0;  // safe tail source
      const float4 v = *(const float4*)&X[(r0 + src) * K + k0 + scol];
      *(float4*)&Xl[row * 32 + scol] = v;
    }
    __syncthreads();
#pragma unroll
    for (int kk = 0; kk < 32; kk += 4) {
      const float w0 = Wl[(k0 + kk + 0) * 64 + col];
      const float w1 = Wl[(k0 + kk + 1) * 64 + col];
      const float w2 = Wl[(k0 + kk + 2) * 64 + col];
      const float w3 = Wl[(k0 + kk + 3) * 64 + col];
#pragma unroll
      for (int r = 0; r < 16; ++r) {
        const float4 xv = *(const float4*)&Xl[(r * 4 + rw) * 32 + kk];
        acc[r] = fmaf(xv.w, w3, fmaf(xv.z, w2, fmaf(xv.y, w1, fmaf(xv.x, w0, acc[r]))));
      }
    }
  }
#pragma unroll
  for (int r = 0; r < 16; ++r) {
    const int lr = r * 4 + rw;
    if (lr < rows) {
      const long long row = r0 + lr;
      HS[row * 64 + col] = f2bf(dinv[row] * acc[r]);
    }
  }
}

// ---- out[i] = relu(dinv[i]*(hs[i] + sum_{src in(i)} hs[src]) + b) ----------
// HS rows are bf16 (128B); gathers move half the bytes of f32.
__global__ void k_agg(const unsigned short* __restrict__ HS, const int* __restrict__ rowptr,
                      const int* __restrict__ csr, const float* __restrict__ dinv,
                      const float* __restrict__ bias, float* __restrict__ OUT, int N) {
  const int lane = threadIdx.x & 63;
  const int wid = threadIdx.x >> 6;
  const int wavesPerBlock = blockDim.x >> 6;
  const float b = bias[lane];
  for (int node = blockIdx.x * wavesPerBlock + wid; node < N;
       node += wavesPerBlock * gridDim.x) {
    const int s0 = rowptr[node], s1 = rowptr[node + 1];
    float a0 = bf2f(HS[(long long)node * 64 + lane]);  // self loop
    float a1 = 0.f, a2 = 0.f, a3 = 0.f;
    for (int base = s0; base < s1; base += 64) {
      int m = s1 - base;
      if (m > 64) m = 64;
      const int idx = (base + lane < s1) ? csr[base + lane] : 0;
      int j = 0;
      for (; j + 8 <= m; j += 8) {
        const int i0 = __shfl(idx, j + 0, 64);
        const int i1 = __shfl(idx, j + 1, 64);
        const int i2 = __shfl(idx, j + 2, 64);
        const int i3 = __shfl(idx, j + 3, 64);
        const int i4 = __shfl(idx, j + 4, 64);
        const int i5 = __shfl(idx, j + 5, 64);
        const int i6 = __shfl(idx, j + 6, 64);
        const int i7 = __shfl(idx, j + 7, 64);
        const unsigned short h0 = HS[(long long)i0 * 64 + lane];
        const unsigned short h1 = HS[(long long)i1 * 64 + lane];
        const unsigned short h2 = HS[(long long)i2 * 64 + lane];
        const unsigned short h3 = HS[(long long)i3 * 64 + lane];
        const unsigned short h4 = HS[(long long)i4 * 64 + lane];
        const unsigned short h5 = HS[(long long)i5 * 64 + lane];
        const unsigned short h6 = HS[(long long)i6 * 64 + lane];
        const unsigned short h7 = HS[(long long)i7 * 64 + lane];
        a0 += bf2f(h0) + bf2f(h4);
        a1 += bf2f(h1) + bf2f(h5);
        a2 += bf2f(h2) + bf2f(h6);
        a3 += bf2f(h3) + bf2f(h7);
      }
      for (; j < m; ++j) {
        const int s = __shfl(idx, j, 64);
        a0 += bf2f(HS[(long long)s * 64 + lane]);
      }
    }
    OUT[(long long)node * 64 + lane] =
        fmaxf(fmaf(dinv[node], (a0 + a1) + (a2 + a3), b), 0.f);
  }
}

// ---- mean pool per graph (batch is sorted) ---------------------------------
__global__ void k_pool(const float* __restrict__ H, const void* __restrict__ batch,
                       const int* __restrict__ flag, float* __restrict__ pooled, int N) {
  __shared__ int se[2];
  __shared__ float red[4][64];
  bool wide = (*flag != 0);
  int g = blockIdx.x;
  if (threadIdx.x < 2) {
    int target = g + threadIdx.x;
    int lo = 0, hi = N;
    while (lo < hi) {
      int mid = (lo + hi) >> 1;
      long long v = wide ? ((const long long*)batch)[mid] : (long long)((const int*)batch)[mid];
      if (v < target) lo = mid + 1; else hi = mid;
    }
    se[threadIdx.x] = lo;
  }
  __syncthreads();
  int s = se[0], e = se[1];
  int lane = threadIdx.x & 63, wid = threadIdx.x >> 6;
  float acc = 0.f;
  for (int r = s + wid; r < e; r += 4) acc += H[(long long)r * 64 + lane];
  red[wid][lane] = acc;
  __syncthreads();
  if (wid == 0) {
    float v = red[0][lane] + red[1][lane] + red[2][lane] + red[3][lane];
    float cnt = (float)(e - s);
    pooled[g * 64 + lane] = v / fmaxf(cnt, 1.f);
  }
}

__global__ void k_classify(const float* __restrict__ pooled, const float* __restrict__ Wc,
                           const float* __restrict__ bc, float* __restrict__ out, int total) {
  int t = blockIdx.x * blockDim.x + threadIdx.x;
  if (t >= total) return;
  int g = t / 10, c = t % 10;
  float acc = bc[c];
#pragma unroll
  for (int h = 0; h < 64; ++h) acc += pooled[g * 64 + h] * Wc[h * 10 + c];
  out[t] = acc;
}

extern "C" void kernel_launch(void* const* d_in, const int* in_sizes, int n_in,
                              void* d_out, int out_size, void* d_ws, size_t ws_size,
                              hipStream_t stream) {
  const float* x = (const float*)d_in[0];
  const void* ei = d_in[1];
  const void* batch = d_in[2];
  const float* W1 = (const float*)d_in[3];
  const float* b1 = (const float*)d_in[4];
  const float* W2 = (const float*)d_in[5];
  const float* b2 = (const float*)d_in[6];
  const float* W3 = (const float*)d_in[7];
  const float* b3 = (const float*)d_in[8];
  const float* Wc = (const float*)d_in[9];
  const float* bc = (const float*)d_in[10];
  float* out = (float*)d_out;

  const int N = in_sizes[0] / 128;
  const int E = in_sizes[1] / 2;
  const int G = out_size / 10;
  const int NB = (N + 2047) / 2048;
  const int cap1 = E / RGRP + E / RGRP / 16 + 256;   // ~6% slack
  const int cap2 = E / NSUB + E / NSUB / 8 + 64;     // ~12.5% slack

  char* W = (char*)d_ws;
  size_t off = 0;
  auto take = [&](size_t b) -> void* {
    void* p = W + off;
    off += (b + 255) & ~(size_t)255;
    return p;
  };
  int* flag = (int*)take(4);
  int* deg = (int*)take((size_t)4 * N);
  int* rowptr = (int*)take((size_t)4 * (N + 1));
  int* bsum = (int*)take((size_t)4 * (NB + 1));
  int* bcur = (int*)take((size_t)4 * RGRP);
  int* scur = (int*)take((size_t)4 * NSUB);
  float* dinv = (float*)take((size_t)4 * N);
  int* csr = (int*)take((size_t)4 * E);
  unsigned short* hs = (unsigned short*)take((size_t)2 * N * 64);
  // two big regions, time-shared: {ebuf}, {ebuf2 -> cur}
  size_t bigBytes = (size_t)8 * RGRP * cap1;
  if ((size_t)8 * NSUB * cap2 > bigBytes) bigBytes = (size_t)8 * NSUB * cap2;
  if ((size_t)4 * N * 64 > bigBytes) bigBytes = (size_t)4 * N * 64;
  void* big0 = take(bigBytes);
  void* big1 = take(bigBytes);
  float* pooled = (float*)take((size_t)4 * G * 64);
  (void)ws_size;

  long long* ebuf = (long long*)big0;
  long long* ebuf2 = (long long*)big1;
  float* cur = (float*)big0;  // layer outputs (f32) reuse big0 after k_bucket
  // NOTE: ebuf2 must stay live until k_csr done; cur first written by k_agg
  // (after k_csr) -> safe to alias cur with big0 (ebuf dead after k_bucket2).

  hipMemsetAsync(bcur, 0, (size_t)4 * RGRP, stream);
  hipMemsetAsync(scur, 0, (size_t)4 * NSUB, stream);

  k_detect<<<1, 256, 0, stream>>>((const unsigned*)ei, flag);
  k_bucket<<<1024, 256, 0, stream>>>(ei, E, flag, cap1, bcur, ebuf, N);
  k_bucket2<<<256, 256, 0, stream>>>(ebuf, bcur, cap1, cap2, scur, ebuf2, N);
  k_subdeg<<<NSUB, 256, 0, stream>>>(ebuf2, scur, cap2, deg, N);
  k_dinv<<<(N + 255) / 256, 256, 0, stream>>>(deg, dinv, N);
  k_scan_a<<<NB, 256, 0, stream>>>(deg, N, bsum);
  k_scan_b<<<1, 64, 0, stream>>>(bsum, NB);
  k_scan_c<<<NB, 256, 0, stream>>>(deg, N, bsum, rowptr, NB);
  k_csr<<<NSUB, 256, 0, stream>>>(ebuf2, scur, cap2, rowptr, csr, N);

  const int TILES = (N + 63) / 64;
  // layer 1: x[N,128] @ W1 -> hs (bf16); aggregate -> cur (f32)
  k_gemm_hs<128><<<TILES, 256, 0, stream>>>(x, W1, dinv, hs, N);
  k_agg<<<4096, 256, 0, stream>>>(hs, rowptr, csr, dinv, b1, cur, N);
  // layer 2
  k_gemm_hs<64><<<TILES, 256, 0, stream>>>(cur, W2, dinv, hs, N);
  k_agg<<<4096, 256, 0, stream>>>(hs, rowptr, csr, dinv, b2, cur, N);
  // layer 3
  k_gemm_hs<64><<<TILES, 256, 0, stream>>>(cur, W3, dinv, hs, N);
  k_agg<<<4096, 256, 0, stream>>>(hs, rowptr, csr, dinv, b3, cur, N);

  k_pool<<<G, 256, 0, stream>>>(cur, batch, flag, pooled, N);
  k_classify<<<(G * 10 + 255) / 256, 256, 0, stream>>>(pooled, Wc, bc, out, G * 10);
}

// Round 9
// 433.231 us; speedup vs baseline: 1.9584x; 1.2461x over previous
//
#include <hip/hip_runtime.h>

// ---------------------------------------------------------------------------
// MalwareGNN: 3-layer GCN (transform -> normalized aggregate) + mean pool + FC
//   * detect int32 vs int64 indices on device (flag in ws)
//   * CSR build, NO global-atomic histograms, NO write amplification:
//       p1 k_bucket : 8 capacity-sliced range buckets of (dst,src) pairs
//       p2 k_bucket2: each range -> 64 capacity-sliced sub-buckets (512 total)
//       p3 k_subdeg : block-per-sub-bucket LDS histogram -> DENSE deg writes
//       scan        : deg -> rowptr
//       p4 k_csr    : block-per-sub-bucket, LDS cursors = rowptr[d]
//   * per layer: MFMA GEMM hs = bf16(dinv*(X@W)): 64x64 tile/block, X and W^T
//     staged bf16 in XOR-swizzled LDS; mfma_f32_16x16x32_bf16; A/B frags use
//     identical slot->k mapping (k-permutation-invariant => only C/D layout
//     must be exact: col=lane&15, row=(lane>>4)*4+reg, verified)
//   * gather-aggregate: wave-per-node, lane = feature, 8x unrolled gathers
//   * self-loops analytic: out = relu(dinv*(hs[i]+sum hs[src])+b)
//   * mean-pool via per-graph binary search on sorted batch, then tiny FC
// ---------------------------------------------------------------------------

#define RGRP 8
#define NSUB 512
#define SUB_PER 64   // NSUB / RGRP
#define MAXNODES 256 // >= ceil(N/NSUB); N=100k -> 196

typedef __attribute__((ext_vector_type(8))) short bf16x8;
typedef __attribute__((ext_vector_type(4))) float f32x4;

__device__ __forceinline__ unsigned short f2bf(float x) {
  unsigned u = __float_as_uint(x);
  u += 0x7FFFu + ((u >> 16) & 1u);  // RNE
  return (unsigned short)(u >> 16);
}
__device__ __forceinline__ float bf2f(unsigned short h) {
  return __uint_as_float((unsigned)h << 16);
}

__global__ void k_detect(const unsigned* __restrict__ ei, int* __restrict__ flag) {
  __shared__ int any;
  if (threadIdx.x == 0) any = 0;
  __syncthreads();
  unsigned v = 0;
  for (int i = threadIdx.x; i < 8192; i += blockDim.x) v |= ei[2 * i + 1];
  if (v) atomicOr(&any, 1);
  __syncthreads();
  if (threadIdx.x == 0) *flag = (any == 0) ? 1 : 0;  // 1 => int64 indices
}

__device__ __forceinline__ int load_idx(const void* p, long long i, bool wide) {
  if (wide) {
    long long v = __builtin_nontemporal_load((const long long*)p + i);
    return (int)v;
  }
  return __builtin_nontemporal_load((const int*)p + i);
}

// p1: per-block chunk -> count 8 ranges in LDS, reserve, dense pair writes
__global__ __launch_bounds__(256) void k_bucket(const void* __restrict__ ei, int E,
                                                const int* __restrict__ flag,
                                                int cap1, int* __restrict__ bcur,
                                                long long* __restrict__ ebuf, int N) {
  __shared__ int sh_cnt[RGRP];
  __shared__ int sh_base[RGRP];
  __shared__ int sh_off[RGRP];
  const bool wide = (*flag != 0);
  const int chunk = (E + gridDim.x - 1) / gridDim.x;
  const int c0 = blockIdx.x * chunk;
  const int c1 = (c0 + chunk < E) ? c0 + chunk : E;
  if (threadIdx.x < RGRP) { sh_cnt[threadIdx.x] = 0; sh_off[threadIdx.x] = 0; }
  __syncthreads();
  for (int e = c0 + threadIdx.x; e < c1; e += 256) {
    const int d = load_idx(ei, (long long)E + e, wide);
    const int r = (int)(((long long)d * RGRP) / N);
    atomicAdd(&sh_cnt[r], 1);
  }
  __syncthreads();
  if (threadIdx.x < RGRP)
    sh_base[threadIdx.x] = atomicAdd(&bcur[threadIdx.x], sh_cnt[threadIdx.x]);
  __syncthreads();
  const long long cap = (long long)RGRP * cap1;
  for (int e = c0 + threadIdx.x; e < c1; e += 256) {
    const int d = load_idx(ei, (long long)E + e, wide);
    const int s = load_idx(ei, e, wide);
    const int r = (int)(((long long)d * RGRP) / N);
    const int o = atomicAdd(&sh_off[r], 1);
    long long pos = (long long)r * cap1 + sh_base[r] + o;
    if (pos >= cap) pos = cap - 1;  // paranoia clamp (slack makes this dead)
    ebuf[pos] = ((long long)(unsigned)d << 32) | (unsigned)s;
  }
}

// p2: range bucket -> 64 capacity-sliced sub-buckets
__global__ __launch_bounds__(256) void k_bucket2(const long long* __restrict__ ebuf,
                                                 const int* __restrict__ bcur,
                                                 int cap1, int cap2,
                                                 int* __restrict__ scur,
                                                 long long* __restrict__ ebuf2, int N) {
  __shared__ int cnt[SUB_PER];
  __shared__ int base[SUB_PER];
  __shared__ int off[SUB_PER];
  const int r = blockIdx.x & (RGRP - 1);
  const int cb = blockIdx.x >> 3;
  const int nch = gridDim.x >> 3;
  const long long e0 = (long long)r * cap1;
  const long long e1 = e0 + bcur[r];
  const int total = (int)(e1 - e0);
  const int chunk = (total + nch - 1) / nch;
  const long long c0 = e0 + (long long)cb * chunk;
  long long c1 = c0 + chunk;
  if (c1 > e1) c1 = e1;
  if (threadIdx.x < SUB_PER) { cnt[threadIdx.x] = 0; off[threadIdx.x] = 0; }
  __syncthreads();
  for (long long e = c0 + threadIdx.x; e < c1; e += 256) {
    const int d = (int)(ebuf[e] >> 32);
    const int ls = (int)(((long long)d * NSUB) / N) - r * SUB_PER;
    atomicAdd(&cnt[ls], 1);
  }
  __syncthreads();
  if (threadIdx.x < SUB_PER) {
    const int s = r * SUB_PER + threadIdx.x;
    base[threadIdx.x] = atomicAdd(&scur[s], cnt[threadIdx.x]);
  }
  __syncthreads();
  const long long cap = (long long)NSUB * cap2;
  for (long long e = c0 + threadIdx.x; e < c1; e += 256) {
    const long long v = ebuf[e];
    const int d = (int)(v >> 32);
    const int ls = (int)(((long long)d * NSUB) / N) - r * SUB_PER;
    const int o = atomicAdd(&off[ls], 1);
    long long pos = (long long)(r * SUB_PER + ls) * cap2 + base[ls] + o;
    if (pos >= cap) pos = cap - 1;  // paranoia clamp
    ebuf2[pos] = v;
  }
}

// p3: per-sub-bucket LDS histogram -> dense deg writes (no global atomics)
__global__ __launch_bounds__(256) void k_subdeg(const long long* __restrict__ ebuf2,
                                                const int* __restrict__ scur, int cap2,
                                                int* __restrict__ deg, int N) {
  __shared__ int hist[MAXNODES];
  const int s = blockIdx.x;
  int nlo = (int)(((long long)N * s + NSUB - 1) / NSUB);
  int nhi = (int)(((long long)N * (s + 1) + NSUB - 1) / NSUB);
  if (nhi > N) nhi = N;
  const int nn = nhi - nlo;
  for (int i = threadIdx.x; i < nn; i += 256) hist[i] = 0;
  __syncthreads();
  const long long e0 = (long long)s * cap2;
  const long long e1 = e0 + scur[s];
  for (long long e = e0 + threadIdx.x; e < e1; e += 256) {
    const int d = (int)(__builtin_nontemporal_load(&ebuf2[e]) >> 32);
    atomicAdd(&hist[d - nlo], 1);
  }
  __syncthreads();
  for (int i = threadIdx.x; i < nn; i += 256) deg[nlo + i] = hist[i];
}

__global__ void k_dinv(const int* __restrict__ deg, float* __restrict__ dinv, int N) {
  int i = blockIdx.x * blockDim.x + threadIdx.x;
  if (i < N) dinv[i] = rsqrtf((float)(deg[i] + 1));  // +1 self loop
}

// ---- exclusive scan of deg[N] -> rowptr[N+1], 2048 items/block -------------
__global__ void k_scan_a(const int* __restrict__ deg, int N, int* __restrict__ bsum) {
  __shared__ int sh[256];
  int base = blockIdx.x * 2048;
  int s = 0;
  for (int i = threadIdx.x; i < 2048; i += 256) {
    int idx = base + i;
    s += (idx < N) ? deg[idx] : 0;
  }
  sh[threadIdx.x] = s;
  __syncthreads();
  for (int off = 128; off > 0; off >>= 1) {
    if (threadIdx.x < off) sh[threadIdx.x] += sh[threadIdx.x + off];
    __syncthreads();
  }
  if (threadIdx.x == 0) bsum[blockIdx.x] = sh[0];
}

__global__ void k_scan_b(int* __restrict__ bsum, int nb) {
  if (threadIdx.x == 0) {
    int run = 0;
    for (int i = 0; i < nb; ++i) { int v = bsum[i]; bsum[i] = run; run += v; }
    bsum[nb] = run;
  }
}

__global__ void k_scan_c(const int* __restrict__ deg, int N, const int* __restrict__ bsum,
                         int* __restrict__ rowptr, int nb) {
  __shared__ int sh[256];
  int base = blockIdx.x * 2048;
  int v[8];
  int s = 0;
#pragma unroll
  for (int j = 0; j < 8; ++j) {
    int idx = base + threadIdx.x * 8 + j;
    v[j] = (idx < N) ? deg[idx] : 0;
    s += v[j];
  }
  sh[threadIdx.x] = s;
  __syncthreads();
  for (int off = 1; off < 256; off <<= 1) {
    int t = (threadIdx.x >= off) ? sh[threadIdx.x - off] : 0;
    __syncthreads();
    sh[threadIdx.x] += t;
    __syncthreads();
  }
  int excl = (threadIdx.x ? sh[threadIdx.x - 1] : 0) + bsum[blockIdx.x];
#pragma unroll
  for (int j = 0; j < 8; ++j) {
    int idx = base + threadIdx.x * 8 + j;
    if (idx < N) rowptr[idx] = excl;
    excl += v[j];
  }
  if (blockIdx.x == gridDim.x - 1 && threadIdx.x == 255) rowptr[N] = bsum[nb];
}

// p4: block-per-sub-bucket; LDS cursors start at rowptr[d]
__global__ __launch_bounds__(256) void k_csr(const long long* __restrict__ ebuf2,
                                             const int* __restrict__ scur, int cap2,
                                             const int* __restrict__ rowptr,
                                             int* __restrict__ csr, int N) {
  __shared__ int lcur[MAXNODES];
  const int s = blockIdx.x;
  int nlo = (int)(((long long)N * s + NSUB - 1) / NSUB);
  int nhi = (int)(((long long)N * (s + 1) + NSUB - 1) / NSUB);
  if (nhi > N) nhi = N;
  const int nn = nhi - nlo;
  for (int i = threadIdx.x; i < nn; i += 256) lcur[i] = rowptr[nlo + i];
  __syncthreads();
  const long long e0 = (long long)s * cap2;
  const long long e1 = e0 + scur[s];
  for (long long e = e0 + threadIdx.x; e < e1; e += 256) {
    const long long v = __builtin_nontemporal_load(&ebuf2[e]);
    const int d = (int)(v >> 32);
    const int pos = atomicAdd(&lcur[d - nlo], 1);
    csr[pos] = (int)v;
  }
}

// ---- HS = bf16(dinv * (X @ W)) via MFMA ------------------------------------
// block = 64x64 tile, 4 waves; wave w owns rows [w*16, w*16+16).
// X (f32 global) and W^T staged as bf16 in XOR-swizzled LDS (16B chunk index
// XOR'd with row&7 -> A/B frag ds_read_b128 is ~2-way, free).
// A frag: lane l slot j = X[w*16+(l&15)][kk*32 + (l>>4)*8 + j]
// B frag: lane l slot j = W[kk*32 + (l>>4)*8 + j][n0*16+(l&15)]  (same k map)
// D: col = lane&15, row = (lane>>4)*4 + reg  (verified layout)
template <int K>
__global__ __launch_bounds__(256) void k_gemm_mfma(const float* __restrict__ X,
                                                   const float* __restrict__ Wg,
                                                   const float* __restrict__ dinv,
                                                   unsigned short* __restrict__ HS,
                                                   int N) {
  __shared__ short Xl[64 * K];
  __shared__ short Wt[64 * K];
  const int t = threadIdx.x;
  const long long r0 = (long long)blockIdx.x * 64;
  const int rows = (int)((N - r0) < 64 ? (N - r0) : 64);

  // stage W^T (bf16, swizzled): Wt[n][k]
  for (int idx = t; idx < K * 64; idx += 256) {
    const int k = idx >> 6, n = idx & 63;
    Wt[n * K + (((k >> 3) ^ (n & 7)) << 3) + (k & 7)] = (short)f2bf(Wg[idx]);
  }
  // stage X (bf16, swizzled): chunks of 8 values
  const int CH = K / 8;
#pragma unroll
  for (int p = 0; p < K / 32; ++p) {
    const int c = p * 256 + t;  // c < 64*CH
    const int row = c / CH, ch = c % CH;
    const int src = (row < rows) ? row : 0;
    const float4 v0 = *(const float4*)&X[(r0 + src) * K + ch * 8];
    const float4 v1 = *(const float4*)&X[(r0 + src) * K + ch * 8 + 4];
    bf16x8 h;
    h[0] = (short)f2bf(v0.x); h[1] = (short)f2bf(v0.y);
    h[2] = (short)f2bf(v0.z); h[3] = (short)f2bf(v0.w);
    h[4] = (short)f2bf(v1.x); h[5] = (short)f2bf(v1.y);
    h[6] = (short)f2bf(v1.z); h[7] = (short)f2bf(v1.w);
    *(bf16x8*)&Xl[row * K + ((ch ^ (row & 7)) << 3)] = h;
  }
  __syncthreads();

  const int lane = t & 63, w = t >> 6;
  const int lo = lane & 15, hi = lane >> 4;
  const int rowa = w * 16 + lo;

  f32x4 acc[4];
#pragma unroll
  for (int i = 0; i < 4; ++i) acc[i] = (f32x4){0.f, 0.f, 0.f, 0.f};

  bf16x8 a[K / 32];
#pragma unroll
  for (int kk = 0; kk < K / 32; ++kk)
    a[kk] = *(const bf16x8*)&Xl[rowa * K + (((kk * 4 + hi) ^ (rowa & 7)) << 3)];

#pragma unroll
  for (int n0 = 0; n0 < 4; ++n0) {
    const int n = n0 * 16 + lo;
#pragma unroll
    for (int kk = 0; kk < K / 32; ++kk) {
      const bf16x8 b = *(const bf16x8*)&Wt[n * K + (((kk * 4 + hi) ^ (n & 7)) << 3)];
      acc[n0] = __builtin_amdgcn_mfma_f32_16x16x32_bf16(a[kk], b, acc[n0], 0, 0, 0);
    }
  }

  float dv[4];
#pragma unroll
  for (int r = 0; r < 4; ++r) {
    const int rr = w * 16 + hi * 4 + r;
    dv[r] = dinv[r0 + (rr < rows ? rr : 0)];
  }
#pragma unroll
  for (int n0 = 0; n0 < 4; ++n0) {
#pragma unroll
    for (int r = 0; r < 4; ++r) {
      const int rr = w * 16 + hi * 4 + r;
      if (rr < rows)
        HS[(r0 + rr) * 64 + n0 * 16 + lo] = f2bf(dv[r] * acc[n0][r]);
    }
  }
}

// ---- out[i] = relu(dinv[i]*(hs[i] + sum_{src in(i)} hs[src]) + b) ----------
// HS rows are bf16 (128B); gathers move half the bytes of f32.
__global__ void k_agg(const unsigned short* __restrict__ HS, const int* __restrict__ rowptr,
                      const int* __restrict__ csr, const float* __restrict__ dinv,
                      const float* __restrict__ bias, float* __restrict__ OUT, int N) {
  const int lane = threadIdx.x & 63;
  const int wid = threadIdx.x >> 6;
  const int wavesPerBlock = blockDim.x >> 6;
  const float b = bias[lane];
  for (int node = blockIdx.x * wavesPerBlock + wid; node < N;
       node += wavesPerBlock * gridDim.x) {
    const int s0 = rowptr[node], s1 = rowptr[node + 1];
    float a0 = bf2f(HS[(long long)node * 64 + lane]);  // self loop
    float a1 = 0.f, a2 = 0.f, a3 = 0.f;
    for (int base = s0; base < s1; base += 64) {
      int m = s1 - base;
      if (m > 64) m = 64;
      const int idx = (base + lane < s1) ? csr[base + lane] : 0;
      int j = 0;
      for (; j + 8 <= m; j += 8) {
        const int i0 = __shfl(idx, j + 0, 64);
        const int i1 = __shfl(idx, j + 1, 64);
        const int i2 = __shfl(idx, j + 2, 64);
        const int i3 = __shfl(idx, j + 3, 64);
        const int i4 = __shfl(idx, j + 4, 64);
        const int i5 = __shfl(idx, j + 5, 64);
        const int i6 = __shfl(idx, j + 6, 64);
        const int i7 = __shfl(idx, j + 7, 64);
        const unsigned short h0 = HS[(long long)i0 * 64 + lane];
        const unsigned short h1 = HS[(long long)i1 * 64 + lane];
        const unsigned short h2 = HS[(long long)i2 * 64 + lane];
        const unsigned short h3 = HS[(long long)i3 * 64 + lane];
        const unsigned short h4 = HS[(long long)i4 * 64 + lane];
        const unsigned short h5 = HS[(long long)i5 * 64 + lane];
        const unsigned short h6 = HS[(long long)i6 * 64 + lane];
        const unsigned short h7 = HS[(long long)i7 * 64 + lane];
        a0 += bf2f(h0) + bf2f(h4);
        a1 += bf2f(h1) + bf2f(h5);
        a2 += bf2f(h2) + bf2f(h6);
        a3 += bf2f(h3) + bf2f(h7);
      }
      for (; j < m; ++j) {
        const int s = __shfl(idx, j, 64);
        a0 += bf2f(HS[(long long)s * 64 + lane]);
      }
    }
    OUT[(long long)node * 64 + lane] =
        fmaxf(fmaf(dinv[node], (a0 + a1) + (a2 + a3), b), 0.f);
  }
}

// ---- mean pool per graph (batch is sorted) ---------------------------------
__global__ void k_pool(const float* __restrict__ H, const void* __restrict__ batch,
                       const int* __restrict__ flag, float* __restrict__ pooled, int N) {
  __shared__ int se[2];
  __shared__ float red[4][64];
  bool wide = (*flag != 0);
  int g = blockIdx.x;
  if (threadIdx.x < 2) {
    int target = g + threadIdx.x;
    int lo = 0, hi = N;
    while (lo < hi) {
      int mid = (lo + hi) >> 1;
      long long v = wide ? ((const long long*)batch)[mid] : (long long)((const int*)batch)[mid];
      if (v < target) lo = mid + 1; else hi = mid;
    }
    se[threadIdx.x] = lo;
  }
  __syncthreads();
  int s = se[0], e = se[1];
  int lane = threadIdx.x & 63, wid = threadIdx.x >> 6;
  float acc = 0.f;
  for (int r = s + wid; r < e; r += 4) acc += H[(long long)r * 64 + lane];
  red[wid][lane] = acc;
  __syncthreads();
  if (wid == 0) {
    float v = red[0][lane] + red[1][lane] + red[2][lane] + red[3][lane];
    float cnt = (float)(e - s);
    pooled[g * 64 + lane] = v / fmaxf(cnt, 1.f);
  }
}

__global__ void k_classify(const float* __restrict__ pooled, const float* __restrict__ Wc,
                           const float* __restrict__ bc, float* __restrict__ out, int total) {
  int t = blockIdx.x * blockDim.x + threadIdx.x;
  if (t >= total) return;
  int g = t / 10, c = t % 10;
  float acc = bc[c];
#pragma unroll
  for (int h = 0; h < 64; ++h) acc += pooled[g * 64 + h] * Wc[h * 10 + c];
  out[t] = acc;
}

extern "C" void kernel_launch(void* const* d_in, const int* in_sizes, int n_in,
                              void* d_out, int out_size, void* d_ws, size_t ws_size,
                              hipStream_t stream) {
  const float* x = (const float*)d_in[0];
  const void* ei = d_in[1];
  const void* batch = d_in[2];
  const float* W1 = (const float*)d_in[3];
  const float* b1 = (const float*)d_in[4];
  const float* W2 = (const float*)d_in[5];
  const float* b2 = (const float*)d_in[6];
  const float* W3 = (const float*)d_in[7];
  const float* b3 = (const float*)d_in[8];
  const float* Wc = (const float*)d_in[9];
  const float* bc = (const float*)d_in[10];
  float* out = (float*)d_out;

  const int N = in_sizes[0] / 128;
  const int E = in_sizes[1] / 2;
  const int G = out_size / 10;
  const int NB = (N + 2047) / 2048;
  const int cap1 = E / RGRP + E / RGRP / 16 + 256;   // ~6% slack
  const int cap2 = E / NSUB + E / NSUB / 8 + 64;     // ~12.5% slack

  char* W = (char*)d_ws;
  size_t off = 0;
  auto take = [&](size_t b) -> void* {
    void* p = W + off;
    off += (b + 255) & ~(size_t)255;
    return p;
  };
  int* flag = (int*)take(4);
  int* deg = (int*)take((size_t)4 * N);
  int* rowptr = (int*)take((size_t)4 * (N + 1));
  int* bsum = (int*)take((size_t)4 * (NB + 1));
  int* bcur = (int*)take((size_t)4 * RGRP);
  int* scur = (int*)take((size_t)4 * NSUB);
  float* dinv = (float*)take((size_t)4 * N);
  int* csr = (int*)take((size_t)4 * E);
  unsigned short* hs = (unsigned short*)take((size_t)2 * N * 64);
  // two big regions, time-shared: {ebuf}, {ebuf2 -> cur}
  size_t bigBytes = (size_t)8 * RGRP * cap1;
  if ((size_t)8 * NSUB * cap2 > bigBytes) bigBytes = (size_t)8 * NSUB * cap2;
  if ((size_t)4 * N * 64 > bigBytes) bigBytes = (size_t)4 * N * 64;
  void* big0 = take(bigBytes);
  void* big1 = take(bigBytes);
  float* pooled = (float*)take((size_t)4 * G * 64);
  (void)ws_size;

  long long* ebuf = (long long*)big0;
  long long* ebuf2 = (long long*)big1;
  float* cur = (float*)big0;  // layer outputs (f32) reuse big0 after k_bucket2
  // ebuf dead after k_bucket2; ebuf2 live until k_csr; cur first written by
  // k_agg (after k_csr) -> aliasing is safe.

  hipMemsetAsync(bcur, 0, (size_t)4 * RGRP, stream);
  hipMemsetAsync(scur, 0, (size_t)4 * NSUB, stream);

  k_detect<<<1, 256, 0, stream>>>((const unsigned*)ei, flag);
  k_bucket<<<1024, 256, 0, stream>>>(ei, E, flag, cap1, bcur, ebuf, N);
  k_bucket2<<<256, 256, 0, stream>>>(ebuf, bcur, cap1, cap2, scur, ebuf2, N);
  k_subdeg<<<NSUB, 256, 0, stream>>>(ebuf2, scur, cap2, deg, N);
  k_dinv<<<(N + 255) / 256, 256, 0, stream>>>(deg, dinv, N);
  k_scan_a<<<NB, 256, 0, stream>>>(deg, N, bsum);
  k_scan_b<<<1, 64, 0, stream>>>(bsum, NB);
  k_scan_c<<<NB, 256, 0, stream>>>(deg, N, bsum, rowptr, NB);
  k_csr<<<NSUB, 256, 0, stream>>>(ebuf2, scur, cap2, rowptr, csr, N);

  const int TILES = (N + 63) / 64;
  // layer 1: x[N,128] @ W1 -> hs (bf16); aggregate -> cur (f32)
  k_gemm_mfma<128><<<TILES, 256, 0, stream>>>(x, W1, dinv, hs, N);
  k_agg<<<4096, 256, 0, stream>>>(hs, rowptr, csr, dinv, b1, cur, N);
  // layer 2
  k_gemm_mfma<64><<<TILES, 256, 0, stream>>>(cur, W2, dinv, hs, N);
  k_agg<<<4096, 256, 0, stream>>>(hs, rowptr, csr, dinv, b2, cur, N);
  // layer 3
  k_gemm_mfma<64><<<TILES, 256, 0, stream>>>(cur, W3, dinv, hs, N);
  k_agg<<<4096, 256, 0, stream>>>(hs, rowptr, csr, dinv, b3, cur, N);

  k_pool<<<G, 256, 0, stream>>>(cur, batch, flag, pooled, N);
  k_classify<<<(G * 10 + 255) / 256, 256, 0, stream>>>(pooled, Wc, bc, out, G * 10);
}